// Round 3
// baseline (624.120 us; speedup 1.0000x reference)
//
#include <hip/hip_runtime.h>
#include <stdint.h>
#include <stddef.h>

// Problem: AdaConv2d  B=8 C=256 H=W=128 G=32 CPG=8 K=3 OUT=256
// Pipeline: instance-norm -> per-sample adaptive grouped 3x3 (+1x1 grouped +bias)
//           -> static 3x3 conv 256->256, reflect padding everywhere.
//
// z intermediate layout: [B][G][H][W][8] bf16 (group-blocked channels-last).
// final conv = bf16 MFMA implicit GEMM:
//   - A (z rows) LDS double-buffered, ONE barrier per K-step (12 total)
//   - B (weights, 1.2 MB, L2-resident) loaded global->VGPR per wave, no LDS.
//     ALL B loads issue BEFORE the A prefetch (vmcnt is FIFO: waiting on a B set
//     must never imply waiting on the HBM A prefetch). 3 disjoint B register
//     sets -- no WAR reuse, so all 24 loads issue back-to-back.
//   - A LDS chunk = w*8 + (gq ^ (w&7))  (0-conflict pattern), via
//     pre-swizzled global source (both-sides-or-neither rule).
// ada conv  = 8-row-tiled VALU kernel: LDS-staged normalized input, SGPR weights.

typedef __attribute__((ext_vector_type(8))) short   s16x8;  // 8 bf16 in 4 VGPRs
typedef __attribute__((ext_vector_type(4))) float   f32x4;

#define NB   8
#define NC   256
#define NH   128
#define NW   128
#define NG   32
#define CPG  8
#define NOUT 256
#define HWPLANE (NH*NW)          // 16384

__device__ __forceinline__ unsigned short f2bf(float f) {
    union { float f; unsigned u; } v; v.f = f;
    unsigned u = v.u;
    u += 0x7fffu + ((u >> 16) & 1u);   // RNE
    return (unsigned short)(u >> 16);
}

__device__ __forceinline__ int refl128(int i) {
    return i < 0 ? 1 : (i > 127 ? 126 : i);
}

__device__ __forceinline__ void async_load16(const void* g, void* l) {
    __builtin_amdgcn_global_load_lds(
        (const __attribute__((address_space(1))) unsigned int*)g,
        (__attribute__((address_space(3))) unsigned int*)l,
        16, 0, 0);
}

// ---------------------------------------------------------------- stats
__global__ __launch_bounds__(256) void stats_k(const float* __restrict__ x,
                                               float* __restrict__ stats) {
    int bc = blockIdx.x, t = threadIdx.x;
    const float4* p = (const float4*)(x + (size_t)bc * HWPLANE);
    float s = 0.f, q = 0.f;
#pragma unroll
    for (int k = 0; k < 16; ++k) {
        float4 v = p[k * 256 + t];
        s += v.x + v.y + v.z + v.w;
        q += v.x * v.x + v.y * v.y + v.z * v.z + v.w * v.w;
    }
    __shared__ float ss[256], sq[256];
    ss[t] = s; sq[t] = q;
    __syncthreads();
    for (int o = 128; o > 0; o >>= 1) {
        if (t < o) { ss[t] += ss[t + o]; sq[t] += sq[t + o]; }
        __syncthreads();
    }
    if (t == 0) {
        float mean = ss[0] * (1.f / HWPLANE);
        float var  = sq[0] * (1.f / HWPLANE) - mean * mean;
        stats[bc * 2]     = mean;
        stats[bc * 2 + 1] = rsqrtf(var + 1e-5f);
    }
}

// ---------------------------------------------------------------- weff
// weff[bg][ic][tap][oc] = sum_j wp[b, g*8+oc, j] * ws[b, g*8+j, ic, tap]
__global__ __launch_bounds__(256) void weff_k(const float* __restrict__ wsp,
                                              const float* __restrict__ wpw,
                                              float* __restrict__ weff) {
    int tid = blockIdx.x * 256 + threadIdx.x;   // 147456 total, exact
    int oc = tid & 7;
    int q  = tid >> 3;
    int t  = q % 9;
    int q2 = q / 9;
    int ic = q2 & 7;
    int bg = q2 >> 3;                           // b*32+g
    float acc = 0.f;
#pragma unroll
    for (int j = 0; j < 8; ++j)
        acc += wpw[(bg * 8 + oc) * 8 + j] * wsp[((bg * 8 + j) * 8 + ic) * 9 + t];
    weff[(size_t)((bg * 8 + ic) * 9 + t) * 8 + oc] = acc;
}

// ---------------------------------------------------------------- weight repack
// conv_w [O][C][3][3] fp32  ->  wtT [tap][O][C] bf16
__global__ __launch_bounds__(256) void repack_k(const float* __restrict__ cw,
                                                unsigned short* __restrict__ wtT) {
    int tid = blockIdx.x * 256 + threadIdx.x;           // 589824 total, exact
    int c = tid & 255;
    int o = (tid >> 8) & 255;
    int t = tid >> 16;                                  // 0..8
    float v = cw[(size_t)(o * NC + c) * 9 + t];
    wtT[((size_t)t * NOUT + o) * NC + c] = f2bf(v);
}

// ---------------------------------------------------------------- fused norm + adaptive conv
// block = (b, g, h-tile of 8): 256 thr. LDS holds 10 normalized rows x 8 ic (40 KB).
// thread = (w, hq): 4 output rows x 8 oc. Weights are block-uniform -> SGPR loads.
// z written [B][G][H][W][8] bf16 -> stores fully coalesced (lane stride 16 B).
__global__ __launch_bounds__(256) void ada_k(const float* __restrict__ x,
                                             const float* __restrict__ stats,
                                             const float* __restrict__ weff,
                                             const float* __restrict__ bias,
                                             unsigned short* __restrict__ z) {
    __shared__ float sx[CPG][10][NW];       // 40 KB
    const int bx = blockIdx.x;
    const int ht = bx & 15;
    const int g  = (bx >> 4) & 31;
    const int b  = bx >> 9;
    const int h0 = ht * 8;

    // stage + normalize 10 rows x 8 ic (2560 float4 loads, coalesced)
#pragma unroll
    for (int it = 0; it < 10; ++it) {
        int p   = it * 256 + threadIdx.x;   // 0..2559
        int ic  = p / 320;
        int rem = p - ic * 320;
        int row = rem >> 5;
        int w4  = rem & 31;
        int cg  = g * 8 + ic;
        float mean = stats[(b * NC + cg) * 2];
        float rstd = stats[(b * NC + cg) * 2 + 1];
        int rr = refl128(h0 - 1 + row);
        const float4* xp4 = (const float4*)(x + (size_t)(b * NC + cg) * HWPLANE + rr * NW);
        float4 v = xp4[w4];
        float4 n = { (v.x - mean) * rstd, (v.y - mean) * rstd,
                     (v.z - mean) * rstd, (v.w - mean) * rstd };
        *(float4*)&sx[ic][row][w4 * 4] = n;
    }
    __syncthreads();

    const int w  = threadIdx.x & 127;
    const int hq = threadIdx.x >> 7;        // 0/1 -> rows hq*4 .. hq*4+3

    const float* wbase = weff + (size_t)(b * NG + g) * 576;   // block-uniform
    const float* bp    = bias + b * NC + g * 8;               // block-uniform

    float acc[4][8];
#pragma unroll
    for (int r = 0; r < 4; ++r)
#pragma unroll
        for (int oc = 0; oc < 8; ++oc) acc[r][oc] = bp[oc];

#pragma unroll
    for (int ic = 0; ic < CPG; ++ic) {
#pragma unroll
        for (int dw = 0; dw < 3; ++dw) {
            int wc = w + dw - 1;
            wc = wc < 0 ? 1 : (wc > 127 ? 126 : wc);
            float xr[6];
#pragma unroll
            for (int rr = 0; rr < 6; ++rr) xr[rr] = sx[ic][hq * 4 + rr][wc];
#pragma unroll
            for (int dh = 0; dh < 3; ++dh) {
                const float* wv = wbase + (ic * 9 + dh * 3 + dw) * 8;
#pragma unroll
                for (int r = 0; r < 4; ++r)
#pragma unroll
                    for (int oc = 0; oc < 8; ++oc)
                        acc[r][oc] += wv[oc] * xr[r + dh];
            }
        }
    }

#pragma unroll
    for (int r = 0; r < 4; ++r) {
        int h = h0 + hq * 4 + r;
        unsigned short ob[8];
#pragma unroll
        for (int oc = 0; oc < 8; ++oc) ob[oc] = f2bf(acc[r][oc]);
        uint4 pk;
        pk.x = (unsigned)ob[0] | ((unsigned)ob[1] << 16);
        pk.y = (unsigned)ob[2] | ((unsigned)ob[3] << 16);
        pk.z = (unsigned)ob[4] | ((unsigned)ob[5] << 16);
        pk.w = (unsigned)ob[6] | ((unsigned)ob[7] << 16);
        // z[b][g][h][w][0..7] -- consecutive lanes (w) 16 B apart: coalesced
        *(uint4*)(z + (size_t)(((b * NG + g) * NH + h) * NW + w) * 8) = pk;
    }
}

// ---------------------------------------------------------------- final conv (MFMA implicit GEMM, 1 barrier/K-step)
// grid 2048: b = id&7 (XCD pin), j = id>>3, nb = j&1 (oc half), h = j>>1.
// block 256 thr / 4 waves, tile 128 w x 128 oc, wave 64x64, K-step = 64 ch (1 tap row).
// LDS: A double-buffered 2x16 KB. B: global->VGPR (wtT L2-resident per XCD).
// Issue order per K-step: 24 B loads (3 disjoint sets) -> sched_barrier ->
// A prefetch (global_load_lds) -> 3 MFMA clusters -> ONE __syncthreads.
// vmcnt FIFO: B-set waits never cover the A prefetch; A drains only at barrier,
// hidden by sibling resident blocks.
__global__ __launch_bounds__(256) void final_k(const unsigned short* __restrict__ z,
                                               const unsigned short* __restrict__ wtT,
                                               const float* __restrict__ cb,
                                               float* __restrict__ out) {
    __shared__ s16x8 sAv[2][1024];     // 128 w x 8 gq chunks (16 B), XOR-swizzled

    const int id = blockIdx.x;
    const int b  = id & 7;
    const int jb = id >> 3;
    const int nb = jb & 1;
    const int h  = jb >> 1;

    const int tid  = threadIdx.x;
    const int wv   = tid >> 6;
    const int lane = tid & 63;
    const int l15  = lane & 15;
    const int quad = lane >> 4;
    const int mo   = (wv & 1) << 6;          // w offset of wave tile
    const int nol  = (wv >> 1) << 6;         // oc offset within 128-oc block tile
    const int n0   = (nb << 7) + nol;        // global oc base of wave tile

    // A staging: LDS chunk ch = w*8 + s holds plane gq = s ^ (w&7), bytes w*16 of
    // that plane's row segment. Source pre-swizzled; dest linear (wave base + lane*16).
    int srcA[4], ldsoff[4];
#pragma unroll
    for (int it = 0; it < 4; ++it) {
        int ch = it * 256 + tid;
        int w_ = ch >> 3, s = ch & 7;
        int gq = s ^ (w_ & 7);
        srcA[it]   = gq * 262144 + w_ * 16;  // plane (g) stride 256 KB
        ldsoff[it] = it * 256 + wv * 64;     // chunk index of wave's uniform base
    }

    // A read offsets (0-conflict pattern)
    int aoff[3][4][2];
#pragma unroll
    for (int dw = 0; dw < 3; ++dw)
#pragma unroll
        for (int i = 0; i < 4; ++i) {
            int w_ = refl128(mo + 16 * i + l15 + dw - 1);
#pragma unroll
            for (int kk = 0; kk < 2; ++kk) {
                int gq = kk * 4 + quad;
                aoff[dw][i][kk] = w_ * 8 + (gq ^ (w_ & 7));
            }
        }

    // B register-load byte offsets within one tap's [O][C] slab
    int boffr[4][2];
#pragma unroll
    for (int j = 0; j < 4; ++j) {
        int oc_l = nol + 16 * j + l15;       // oc row within 128-row half
#pragma unroll
        for (int kk = 0; kk < 2; ++kk)
            boffr[j][kk] = oc_l * 512 + (kk * 4 + quad) * 16;
    }

    const char* zb = (const char*)z + (size_t)b * (NG * NH * NW * CPG * 2);  // 8 MB/image
    const char* zr[3];
#pragma unroll
    for (int dh = 0; dh < 3; ++dh)
        zr[dh] = zb + (size_t)refl128(h + dh - 1) * (NW * CPG * 2);          // 2 KB/row seg
    const char* wt = (const char*)wtT + nb * 65536;    // oc-half base; tap stride 131072

    auto stageA = [&](const char* g, int sel) {
#pragma unroll
        for (int it = 0; it < 4; ++it)
            async_load16(g + srcA[it], (void*)(sAv[sel] + ldsoff[it]));
    };
    auto loadB = [&](const char* bt, s16x8 (&bv)[4][2]) {
#pragma unroll
        for (int j = 0; j < 4; ++j)
#pragma unroll
            for (int kk = 0; kk < 2; ++kk)
                bv[j][kk] = *(const s16x8*)(bt + boffr[j][kk]);
    };

    f32x4 acc[4][4] = {};

    auto compute = [&](const int (&ao)[4][2], const s16x8 (&bv)[4][2], int sel) {
        const s16x8* abase = sAv[sel];
        __builtin_amdgcn_s_setprio(1);
#pragma unroll
        for (int kk = 0; kk < 2; ++kk) {
            s16x8 av[4];
#pragma unroll
            for (int i = 0; i < 4; ++i) av[i] = abase[ao[i][kk]];
#pragma unroll
            for (int i = 0; i < 4; ++i)
#pragma unroll
                for (int j = 0; j < 4; ++j)
                    acc[i][j] = __builtin_amdgcn_mfma_f32_16x16x32_bf16(
                        av[i], bv[j][kk], acc[i][j], 0, 0, 0);
        }
        __builtin_amdgcn_s_setprio(0);
    };

    int buf = 0;
    stageA(zr[0], 0);                          // (dh=0, kc=0)
    __syncthreads();

    for (int sc = 0; sc < 12; ++sc) {
        const int dh = sc >> 2, kc = sc & 3;
        const char* bt0 = wt + (size_t)(dh * 3) * 131072 + kc * 128;

        s16x8 bvA[4][2], bvB[4][2], bvC[4][2];
        loadB(bt0,          bvA);              // dw=0
        loadB(bt0 + 131072, bvB);              // dw=1
        loadB(bt0 + 262144, bvC);              // dw=2
        __builtin_amdgcn_sched_barrier(0);     // pin: no B load sinks past stageA
        if (sc < 11) {                         // prefetch next K-step's A tile
            const int sn = sc + 1;
            stageA(zr[sn >> 2] + (size_t)(sn & 3) * 2097152, buf ^ 1);
        }
        compute(aoff[0], bvA, buf);
        compute(aoff[1], bvB, buf);
        compute(aoff[2], bvC, buf);
        __syncthreads();                       // A[buf^1] staged + all waves done with A[buf]
        buf ^= 1;
    }

    // epilogue: D layout col=lane&15 (oc), row=quad*4+reg (w)
#pragma unroll
    for (int j = 0; j < 4; ++j) {
        int oc = n0 + 16 * j + l15;
        float bvl = cb[oc];
#pragma unroll
        for (int i = 0; i < 4; ++i) {
            int w0 = mo + 16 * i + quad * 4;
            float* dst = out + (((size_t)(b * NOUT + oc) * NH + h) * NW + w0);
            f32x4 v = acc[i][j];
            float4 o4 = { v[0] + bvl, v[1] + bvl, v[2] + bvl, v[3] + bvl };
            *(float4*)dst = o4;
        }
    }
}

// ---------------------------------------------------------------- launch
extern "C" void kernel_launch(void* const* d_in, const int* in_sizes, int n_in,
                              void* d_out, int out_size, void* d_ws, size_t ws_size,
                              hipStream_t stream) {
    const float* x   = (const float*)d_in[0];
    const float* wsp = (const float*)d_in[1];
    const float* wpw = (const float*)d_in[2];
    const float* bia = (const float*)d_in[3];
    const float* cw  = (const float*)d_in[4];
    const float* cb  = (const float*)d_in[5];
    float* out = (float*)d_out;

    // workspace layout (16B aligned):
    //   stats 16 KB | weff 576 KB | wtT 1.13 MB | z 64 MB
    char* ws = (char*)d_ws;
    float*          stats = (float*)ws;                          // 2048*2 f32
    float*          weff  = (float*)(ws + 16384);                // 2048*72 f32
    unsigned short* wtT   = (unsigned short*)(ws + 606208);      // 9*256*256 bf16
    unsigned short* z     = (unsigned short*)(ws + 1785856);     // [8][32][128][128][8] bf16

    stats_k <<<NB * NC, 256, 0, stream>>>(x, stats);
    weff_k  <<<576,     256, 0, stream>>>(wsp, wpw, weff);
    repack_k<<<2304,    256, 0, stream>>>(cw, wtT);
    ada_k   <<<NB * NG * (NH / 8), 256, 0, stream>>>(x, stats, weff, bia, z);
    final_k <<<NB * NH * 2,  256, 0, stream>>>(z, wtT, cb, out);
}

// Round 4
// 496.788 us; speedup vs baseline: 1.2563x; 1.2563x over previous
//
#include <hip/hip_runtime.h>
#include <stdint.h>
#include <stddef.h>

// Problem: AdaConv2d  B=8 C=256 H=W=128 G=32 CPG=8 K=3 OUT=256
// Pipeline: instance-norm -> per-sample adaptive grouped 3x3 (+1x1 grouped +bias)
//           -> static 3x3 conv 256->256, reflect padding everywhere.
//
// z intermediate layout: [B][G][H][W][8] bf16 (group-blocked channels-last).
// final conv = bf16 MFMA implicit GEMM, LDS-tiled, ROUND-0 schedule with M
//   blocked over 2 output rows (512 thr / 8 waves, tile 2h x 128w x 128oc):
//   B-slab LDS staging (48 KB/step) amortized over 2 output rows -- per-CU
//   inbound traffic 6 MB -> 3.84 MB vs the 1-row version.
//   A LDS chunk = row*1024 + w*8 + (gq ^ (w&7))  (0-conflict), pre-swizzled src.
// ada conv  = 8-row-tiled VALU kernel: LDS-staged normalized input, SGPR weights.

typedef __attribute__((ext_vector_type(8))) short   s16x8;  // 8 bf16 in 4 VGPRs
typedef __attribute__((ext_vector_type(4))) float   f32x4;

#define NB   8
#define NC   256
#define NH   128
#define NW   128
#define NG   32
#define CPG  8
#define NOUT 256
#define HWPLANE (NH*NW)          // 16384

__device__ __forceinline__ unsigned short f2bf(float f) {
    union { float f; unsigned u; } v; v.f = f;
    unsigned u = v.u;
    u += 0x7fffu + ((u >> 16) & 1u);   // RNE
    return (unsigned short)(u >> 16);
}

__device__ __forceinline__ int refl128(int i) {
    return i < 0 ? 1 : (i > 127 ? 126 : i);
}

__device__ __forceinline__ void async_load16(const void* g, void* l) {
    __builtin_amdgcn_global_load_lds(
        (const __attribute__((address_space(1))) unsigned int*)g,
        (__attribute__((address_space(3))) unsigned int*)l,
        16, 0, 0);
}

// ---------------------------------------------------------------- stats
__global__ __launch_bounds__(256) void stats_k(const float* __restrict__ x,
                                               float* __restrict__ stats) {
    int bc = blockIdx.x, t = threadIdx.x;
    const float4* p = (const float4*)(x + (size_t)bc * HWPLANE);
    float s = 0.f, q = 0.f;
#pragma unroll
    for (int k = 0; k < 16; ++k) {
        float4 v = p[k * 256 + t];
        s += v.x + v.y + v.z + v.w;
        q += v.x * v.x + v.y * v.y + v.z * v.z + v.w * v.w;
    }
    __shared__ float ss[256], sq[256];
    ss[t] = s; sq[t] = q;
    __syncthreads();
    for (int o = 128; o > 0; o >>= 1) {
        if (t < o) { ss[t] += ss[t + o]; sq[t] += sq[t + o]; }
        __syncthreads();
    }
    if (t == 0) {
        float mean = ss[0] * (1.f / HWPLANE);
        float var  = sq[0] * (1.f / HWPLANE) - mean * mean;
        stats[bc * 2]     = mean;
        stats[bc * 2 + 1] = rsqrtf(var + 1e-5f);
    }
}

// ---------------------------------------------------------------- weff
// weff[bg][ic][tap][oc] = sum_j wp[b, g*8+oc, j] * ws[b, g*8+j, ic, tap]
__global__ __launch_bounds__(256) void weff_k(const float* __restrict__ wsp,
                                              const float* __restrict__ wpw,
                                              float* __restrict__ weff) {
    int tid = blockIdx.x * 256 + threadIdx.x;   // 147456 total, exact
    int oc = tid & 7;
    int q  = tid >> 3;
    int t  = q % 9;
    int q2 = q / 9;
    int ic = q2 & 7;
    int bg = q2 >> 3;                           // b*32+g
    float acc = 0.f;
#pragma unroll
    for (int j = 0; j < 8; ++j)
        acc += wpw[(bg * 8 + oc) * 8 + j] * wsp[((bg * 8 + j) * 8 + ic) * 9 + t];
    weff[(size_t)((bg * 8 + ic) * 9 + t) * 8 + oc] = acc;
}

// ---------------------------------------------------------------- weight repack
// conv_w [O][C][3][3] fp32  ->  wtT [tap][O][C] bf16
__global__ __launch_bounds__(256) void repack_k(const float* __restrict__ cw,
                                                unsigned short* __restrict__ wtT) {
    int tid = blockIdx.x * 256 + threadIdx.x;           // 589824 total, exact
    int c = tid & 255;
    int o = (tid >> 8) & 255;
    int t = tid >> 16;                                  // 0..8
    float v = cw[(size_t)(o * NC + c) * 9 + t];
    wtT[((size_t)t * NOUT + o) * NC + c] = f2bf(v);
}

// ---------------------------------------------------------------- fused norm + adaptive conv
// block = (b, g, h-tile of 8): 256 thr. LDS holds 10 normalized rows x 8 ic (40 KB).
// thread = (w, hq): 4 output rows x 8 oc. Weights are block-uniform -> SGPR loads.
// z written [B][G][H][W][8] bf16 -> stores fully coalesced (lane stride 16 B).
__global__ __launch_bounds__(256) void ada_k(const float* __restrict__ x,
                                             const float* __restrict__ stats,
                                             const float* __restrict__ weff,
                                             const float* __restrict__ bias,
                                             unsigned short* __restrict__ z) {
    __shared__ float sx[CPG][10][NW];       // 40 KB
    const int bx = blockIdx.x;
    const int ht = bx & 15;
    const int g  = (bx >> 4) & 31;
    const int b  = bx >> 9;
    const int h0 = ht * 8;

    // stage + normalize 10 rows x 8 ic (2560 float4 loads, coalesced)
#pragma unroll
    for (int it = 0; it < 10; ++it) {
        int p   = it * 256 + threadIdx.x;   // 0..2559
        int ic  = p / 320;
        int rem = p - ic * 320;
        int row = rem >> 5;
        int w4  = rem & 31;
        int cg  = g * 8 + ic;
        float mean = stats[(b * NC + cg) * 2];
        float rstd = stats[(b * NC + cg) * 2 + 1];
        int rr = refl128(h0 - 1 + row);
        const float4* xp4 = (const float4*)(x + (size_t)(b * NC + cg) * HWPLANE + rr * NW);
        float4 v = xp4[w4];
        float4 n = { (v.x - mean) * rstd, (v.y - mean) * rstd,
                     (v.z - mean) * rstd, (v.w - mean) * rstd };
        *(float4*)&sx[ic][row][w4 * 4] = n;
    }
    __syncthreads();

    const int w  = threadIdx.x & 127;
    const int hq = threadIdx.x >> 7;        // 0/1 -> rows hq*4 .. hq*4+3

    const float* wbase = weff + (size_t)(b * NG + g) * 576;   // block-uniform
    const float* bp    = bias + b * NC + g * 8;               // block-uniform

    float acc[4][8];
#pragma unroll
    for (int r = 0; r < 4; ++r)
#pragma unroll
        for (int oc = 0; oc < 8; ++oc) acc[r][oc] = bp[oc];

#pragma unroll
    for (int ic = 0; ic < CPG; ++ic) {
#pragma unroll
        for (int dw = 0; dw < 3; ++dw) {
            int wc = w + dw - 1;
            wc = wc < 0 ? 1 : (wc > 127 ? 126 : wc);
            float xr[6];
#pragma unroll
            for (int rr = 0; rr < 6; ++rr) xr[rr] = sx[ic][hq * 4 + rr][wc];
#pragma unroll
            for (int dh = 0; dh < 3; ++dh) {
                const float* wv = wbase + (ic * 9 + dh * 3 + dw) * 8;
#pragma unroll
                for (int r = 0; r < 4; ++r)
#pragma unroll
                    for (int oc = 0; oc < 8; ++oc)
                        acc[r][oc] += wv[oc] * xr[r + dh];
            }
        }
    }

#pragma unroll
    for (int r = 0; r < 4; ++r) {
        int h = h0 + hq * 4 + r;
        unsigned short ob[8];
#pragma unroll
        for (int oc = 0; oc < 8; ++oc) ob[oc] = f2bf(acc[r][oc]);
        uint4 pk;
        pk.x = (unsigned)ob[0] | ((unsigned)ob[1] << 16);
        pk.y = (unsigned)ob[2] | ((unsigned)ob[3] << 16);
        pk.z = (unsigned)ob[4] | ((unsigned)ob[5] << 16);
        pk.w = (unsigned)ob[6] | ((unsigned)ob[7] << 16);
        // z[b][g][h][w][0..7] -- consecutive lanes (w) 16 B apart: coalesced
        *(uint4*)(z + (size_t)(((b * NG + g) * NH + h) * NW + w) * 8) = pk;
    }
}

// ---------------------------------------------------------------- final conv (LDS-tiled MFMA implicit GEMM, 2 h-rows/block)
// grid 1024: b = id&7 (XCD pin), j = id>>3, nb = j&1 (oc half), ht = j>>1, h0 = 2*ht.
// block 512 thr / 8 waves, tile (2h x 128w) x 128oc; wave tile 64x64:
//   wsub = wv&3 -> hrow = wsub>>1, wo = (wsub&1)*64; nol = (wv>>2)*64.
// LDS: A 32 KB single (2 rows x 128 w x 8 gq chunks) + B 2x16 KB dbuf = 64 KB
//   -> 2 blocks/CU, 16 waves/CU. B staging shared by 8 waves, amortized over 2 rows.
__global__ __launch_bounds__(512) void final_k(const unsigned short* __restrict__ z,
                                               const unsigned short* __restrict__ wtT,
                                               const float* __restrict__ cb,
                                               float* __restrict__ out) {
    __shared__ s16x8 sAv[2048];        // [row2][w128][gq8] chunks, 32 KB
    __shared__ s16x8 sBv[2][1024];     // 2 x 16 KB

    const int id = blockIdx.x;
    const int b  = id & 7;
    const int jb = id >> 3;
    const int nb = jb & 1;
    const int ht = jb >> 1;
    const int h0 = ht * 2;

    const int tid  = threadIdx.x;
    const int wv   = tid >> 6;               // 0..7
    const int lane = tid & 63;
    const int l15  = lane & 15;
    const int quad = lane >> 4;
    const int wsub = wv & 3;
    const int hrow = wsub >> 1;              // 0/1: output row h0+hrow
    const int wo   = (wsub & 1) << 6;        // w offset of wave tile
    const int nol  = (wv >> 2) << 6;         // oc offset within 128-oc block tile
    const int n0   = (nb << 7) + nol;        // global oc base of wave tile

    // A staging: 2048 chunks, 4 iters x 512 thr. LDS chunk ch = row*1024 + w*8 + s
    // holds plane gq = s ^ (w&7) of z-row (row), bytes w*16. Source pre-swizzled;
    // dest linear (wave-uniform base + lane*16). iters 0-1 -> row 0, 2-3 -> row 1.
    int srcA[4], ldsA[4];
#pragma unroll
    for (int it = 0; it < 4; ++it) {
        int ch = it * 512 + tid;             // 0..2047
        int cw = (ch >> 3) & 127;
        int s  = ch & 7;
        int gq = s ^ (cw & 7);
        srcA[it] = gq * 262144 + cw * 16;    // plane (g) stride 256 KB
        ldsA[it] = it * 512 + wv * 64;       // chunk index of wave's uniform base
    }

    // B staging: 1024 chunks, 2 iters x 512 thr (wtT rows of 512 B, swizzled cols)
    int srcB[2], ldsB[2];
#pragma unroll
    for (int it = 0; it < 2; ++it) {
        int ch = it * 512 + tid;
        int oc = ch >> 3, cp = ch & 7;
        srcB[it] = oc * 512 + ((cp ^ (oc & 7)) << 4);
        ldsB[it] = it * 512 + wv * 64;
    }

    // A read offsets (0-conflict pattern), + wave-uniform row base
    int aoff[3][4][2];
#pragma unroll
    for (int dw = 0; dw < 3; ++dw)
#pragma unroll
        for (int i = 0; i < 4; ++i) {
            int w_ = refl128(wo + 16 * i + l15 + dw - 1);
#pragma unroll
            for (int kk = 0; kk < 2; ++kk) {
                int gq = kk * 4 + quad;
                aoff[dw][i][kk] = hrow * 1024 + w_ * 8 + (gq ^ (w_ & 7));
            }
        }
    int boff[4][2];
#pragma unroll
    for (int j = 0; j < 4; ++j) {
        int oc_l = nol + 16 * j + l15;
#pragma unroll
        for (int kk = 0; kk < 2; ++kk)
            boff[j][kk] = oc_l * 8 + ((kk * 4 + quad) ^ (oc_l & 7));
    }

    const char* zb = (const char*)z + (size_t)b * (NG * NH * NW * CPG * 2);  // 8 MB/image
    const char* zrow[4];
#pragma unroll
    for (int r = 0; r < 4; ++r)
        zrow[r] = zb + (size_t)refl128(h0 + r - 1) * (NW * CPG * 2);         // 2 KB/row seg
    const char* wt = (const char*)wtT + nb * 65536;    // oc-half base; tap stride 131072

    auto stageA = [&](const char* rp0, const char* rp1) {
        async_load16(rp0 + srcA[0], (void*)(sAv + ldsA[0]));
        async_load16(rp0 + srcA[1], (void*)(sAv + ldsA[1]));
        async_load16(rp1 + srcA[2], (void*)(sAv + ldsA[2]));
        async_load16(rp1 + srcA[3], (void*)(sAv + ldsA[3]));
    };
    auto stageB = [&](const char* g, int bsel) {
#pragma unroll
        for (int it = 0; it < 2; ++it)
            async_load16(g + srcB[it], (void*)(sBv[bsel] + ldsB[it]));
    };

    f32x4 acc[4][4] = {};

    auto compute = [&](const int (&ao)[4][2], int bsel) {
        const s16x8* bbase = sBv[bsel];
        __builtin_amdgcn_s_setprio(1);
#pragma unroll
        for (int kk = 0; kk < 2; ++kk) {
            s16x8 av[4], bv[4];
#pragma unroll
            for (int i = 0; i < 4; ++i) av[i] = sAv[ao[i][kk]];
#pragma unroll
            for (int j = 0; j < 4; ++j) bv[j] = bbase[boff[j][kk]];
#pragma unroll
            for (int i = 0; i < 4; ++i)
#pragma unroll
                for (int j = 0; j < 4; ++j)
                    acc[i][j] = __builtin_amdgcn_mfma_f32_16x16x32_bf16(
                        av[i], bv[j], acc[i][j], 0, 0, 0);
        }
        __builtin_amdgcn_s_setprio(0);
    };

    int buf = 0;
    stageA(zrow[0], zrow[1]);                  // (dh=0, kc=0): rows h0-1, h0
    stageB(wt, 0);
    __syncthreads();

    for (int sc = 0; sc < 12; ++sc) {
        const int dh = sc >> 2, kc = sc & 3;
        const char* bt = wt + (size_t)(dh * 3) * 131072 + kc * 128;
        stageB(bt + 131072, buf ^ 1);          // prefetch dw=1
        compute(aoff[0], buf);
        __syncthreads(); buf ^= 1;
        stageB(bt + 262144, buf ^ 1);          // prefetch dw=2
        compute(aoff[1], buf);
        __syncthreads(); buf ^= 1;
        compute(aoff[2], buf);
        __syncthreads();
        if (sc < 11) {                         // stage next (dh,kc): A rows + first B
            const int sn = sc + 1, dhn = sn >> 2, kcn = sn & 3;
            const size_t ko = (size_t)kcn * 2097152;   // kc selects g-block of 8 (2 MB)
            stageA(zrow[dhn] + ko, zrow[dhn + 1] + ko);
            stageB(wt + (size_t)(dhn * 3) * 131072 + kcn * 128, buf ^ 1);
            __syncthreads();
        }
        buf ^= 1;
    }

    // epilogue: D layout col=lane&15 (oc), row=quad*4+reg (w)
    const int h = h0 + hrow;
#pragma unroll
    for (int j = 0; j < 4; ++j) {
        int oc = n0 + 16 * j + l15;
        float bvl = cb[oc];
#pragma unroll
        for (int i = 0; i < 4; ++i) {
            int w0 = wo + 16 * i + quad * 4;
            float* dst = out + (((size_t)(b * NOUT + oc) * NH + h) * NW + w0);
            f32x4 v = acc[i][j];
            float4 o4 = { v[0] + bvl, v[1] + bvl, v[2] + bvl, v[3] + bvl };
            *(float4*)dst = o4;
        }
    }
}

// ---------------------------------------------------------------- launch
extern "C" void kernel_launch(void* const* d_in, const int* in_sizes, int n_in,
                              void* d_out, int out_size, void* d_ws, size_t ws_size,
                              hipStream_t stream) {
    const float* x   = (const float*)d_in[0];
    const float* wsp = (const float*)d_in[1];
    const float* wpw = (const float*)d_in[2];
    const float* bia = (const float*)d_in[3];
    const float* cw  = (const float*)d_in[4];
    const float* cb  = (const float*)d_in[5];
    float* out = (float*)d_out;

    // workspace layout (16B aligned):
    //   stats 16 KB | weff 576 KB | wtT 1.13 MB | z 64 MB
    char* ws = (char*)d_ws;
    float*          stats = (float*)ws;                          // 2048*2 f32
    float*          weff  = (float*)(ws + 16384);                // 2048*72 f32
    unsigned short* wtT   = (unsigned short*)(ws + 606208);      // 9*256*256 bf16
    unsigned short* z     = (unsigned short*)(ws + 1785856);     // [8][32][128][128][8] bf16

    stats_k <<<NB * NC, 256, 0, stream>>>(x, stats);
    weff_k  <<<576,     256, 0, stream>>>(wsp, wpw, weff);
    repack_k<<<2304,    256, 0, stream>>>(cw, wtT);
    ada_k   <<<NB * NG * (NH / 8), 256, 0, stream>>>(x, stats, weff, bia, z);
    final_k <<<NB * NH * 2 / 2, 512, 0, stream>>>(z, wtT, cb, out);
}

// Round 5
// 449.472 us; speedup vs baseline: 1.3886x; 1.1053x over previous
//
#include <hip/hip_runtime.h>
#include <stdint.h>
#include <stddef.h>

// Problem: AdaConv2d  B=8 C=256 H=W=128 G=32 CPG=8 K=3 OUT=256
// Pipeline: instance-norm -> per-sample adaptive grouped 3x3 (+1x1 grouped +bias)
//           -> static 3x3 conv 256->256, reflect padding everywhere.
//
// z intermediate layout: [B][G][H][W][8] bf16 (group-blocked channels-last).
// final conv = bf16 MFMA implicit GEMM with T3+T4 counted-vmcnt schedule:
//   36 sub-steps (dh,kc,dw), ONE raw s_barrier each, vmcnt never drained to 0
//   mid-loop (steady {4,8,8}); B triple-buffered (staged 2 sub-steps ahead),
//   A double-buffered (staged 3 sub-steps ahead, covers HBM latency).
//   A LDS chunk = w*8 + (gq ^ (w&7))  (0-conflict, proven r2-r4), pre-swizzled src.
// ada conv  = 8-row-tiled VALU kernel: LDS-staged normalized input, SGPR weights.

typedef __attribute__((ext_vector_type(8))) short   s16x8;  // 8 bf16 in 4 VGPRs
typedef __attribute__((ext_vector_type(4))) float   f32x4;

#define NB   8
#define NC   256
#define NH   128
#define NW   128
#define NG   32
#define CPG  8
#define NOUT 256
#define HWPLANE (NH*NW)          // 16384

__device__ __forceinline__ unsigned short f2bf(float f) {
    union { float f; unsigned u; } v; v.f = f;
    unsigned u = v.u;
    u += 0x7fffu + ((u >> 16) & 1u);   // RNE
    return (unsigned short)(u >> 16);
}

__device__ __forceinline__ int refl128(int i) {
    return i < 0 ? 1 : (i > 127 ? 126 : i);
}

__device__ __forceinline__ void async_load16(const void* g, void* l) {
    __builtin_amdgcn_global_load_lds(
        (const __attribute__((address_space(1))) unsigned int*)g,
        (__attribute__((address_space(3))) unsigned int*)l,
        16, 0, 0);
}

// ---------------------------------------------------------------- stats
__global__ __launch_bounds__(256) void stats_k(const float* __restrict__ x,
                                               float* __restrict__ stats) {
    int bc = blockIdx.x, t = threadIdx.x;
    const float4* p = (const float4*)(x + (size_t)bc * HWPLANE);
    float s = 0.f, q = 0.f;
#pragma unroll
    for (int k = 0; k < 16; ++k) {
        float4 v = p[k * 256 + t];
        s += v.x + v.y + v.z + v.w;
        q += v.x * v.x + v.y * v.y + v.z * v.z + v.w * v.w;
    }
    __shared__ float ss[256], sq[256];
    ss[t] = s; sq[t] = q;
    __syncthreads();
    for (int o = 128; o > 0; o >>= 1) {
        if (t < o) { ss[t] += ss[t + o]; sq[t] += sq[t + o]; }
        __syncthreads();
    }
    if (t == 0) {
        float mean = ss[0] * (1.f / HWPLANE);
        float var  = sq[0] * (1.f / HWPLANE) - mean * mean;
        stats[bc * 2]     = mean;
        stats[bc * 2 + 1] = rsqrtf(var + 1e-5f);
    }
}

// ---------------------------------------------------------------- weff
// weff[bg][ic][tap][oc] = sum_j wp[b, g*8+oc, j] * ws[b, g*8+j, ic, tap]
__global__ __launch_bounds__(256) void weff_k(const float* __restrict__ wsp,
                                              const float* __restrict__ wpw,
                                              float* __restrict__ weff) {
    int tid = blockIdx.x * 256 + threadIdx.x;   // 147456 total, exact
    int oc = tid & 7;
    int q  = tid >> 3;
    int t  = q % 9;
    int q2 = q / 9;
    int ic = q2 & 7;
    int bg = q2 >> 3;                           // b*32+g
    float acc = 0.f;
#pragma unroll
    for (int j = 0; j < 8; ++j)
        acc += wpw[(bg * 8 + oc) * 8 + j] * wsp[((bg * 8 + j) * 8 + ic) * 9 + t];
    weff[(size_t)((bg * 8 + ic) * 9 + t) * 8 + oc] = acc;
}

// ---------------------------------------------------------------- weight repack
// conv_w [O][C][3][3] fp32  ->  wtT [tap][O][C] bf16
__global__ __launch_bounds__(256) void repack_k(const float* __restrict__ cw,
                                                unsigned short* __restrict__ wtT) {
    int tid = blockIdx.x * 256 + threadIdx.x;           // 589824 total, exact
    int c = tid & 255;
    int o = (tid >> 8) & 255;
    int t = tid >> 16;                                  // 0..8
    float v = cw[(size_t)(o * NC + c) * 9 + t];
    wtT[((size_t)t * NOUT + o) * NC + c] = f2bf(v);
}

// ---------------------------------------------------------------- fused norm + adaptive conv
// block = (b, g, h-tile of 8): 256 thr. LDS holds 10 normalized rows x 8 ic (40 KB).
// thread = (w, hq): 4 output rows x 8 oc. Weights are block-uniform -> SGPR loads.
// z written [B][G][H][W][8] bf16 -> stores fully coalesced (lane stride 16 B).
__global__ __launch_bounds__(256) void ada_k(const float* __restrict__ x,
                                             const float* __restrict__ stats,
                                             const float* __restrict__ weff,
                                             const float* __restrict__ bias,
                                             unsigned short* __restrict__ z) {
    __shared__ float sx[CPG][10][NW];       // 40 KB
    const int bx = blockIdx.x;
    const int ht = bx & 15;
    const int g  = (bx >> 4) & 31;
    const int b  = bx >> 9;
    const int h0 = ht * 8;

    // stage + normalize 10 rows x 8 ic (2560 float4 loads, coalesced)
#pragma unroll
    for (int it = 0; it < 10; ++it) {
        int p   = it * 256 + threadIdx.x;   // 0..2559
        int ic  = p / 320;
        int rem = p - ic * 320;
        int row = rem >> 5;
        int w4  = rem & 31;
        int cg  = g * 8 + ic;
        float mean = stats[(b * NC + cg) * 2];
        float rstd = stats[(b * NC + cg) * 2 + 1];
        int rr = refl128(h0 - 1 + row);
        const float4* xp4 = (const float4*)(x + (size_t)(b * NC + cg) * HWPLANE + rr * NW);
        float4 v = xp4[w4];
        float4 n = { (v.x - mean) * rstd, (v.y - mean) * rstd,
                     (v.z - mean) * rstd, (v.w - mean) * rstd };
        *(float4*)&sx[ic][row][w4 * 4] = n;
    }
    __syncthreads();

    const int w  = threadIdx.x & 127;
    const int hq = threadIdx.x >> 7;        // 0/1 -> rows hq*4 .. hq*4+3

    const float* wbase = weff + (size_t)(b * NG + g) * 576;   // block-uniform
    const float* bp    = bias + b * NC + g * 8;               // block-uniform

    float acc[4][8];
#pragma unroll
    for (int r = 0; r < 4; ++r)
#pragma unroll
        for (int oc = 0; oc < 8; ++oc) acc[r][oc] = bp[oc];

#pragma unroll
    for (int ic = 0; ic < CPG; ++ic) {
#pragma unroll
        for (int dw = 0; dw < 3; ++dw) {
            int wc = w + dw - 1;
            wc = wc < 0 ? 1 : (wc > 127 ? 126 : wc);
            float xr[6];
#pragma unroll
            for (int rr = 0; rr < 6; ++rr) xr[rr] = sx[ic][hq * 4 + rr][wc];
#pragma unroll
            for (int dh = 0; dh < 3; ++dh) {
                const float* wv = wbase + (ic * 9 + dh * 3 + dw) * 8;
#pragma unroll
                for (int r = 0; r < 4; ++r)
#pragma unroll
                    for (int oc = 0; oc < 8; ++oc)
                        acc[r][oc] += wv[oc] * xr[r + dh];
            }
        }
    }

#pragma unroll
    for (int r = 0; r < 4; ++r) {
        int h = h0 + hq * 4 + r;
        unsigned short ob[8];
#pragma unroll
        for (int oc = 0; oc < 8; ++oc) ob[oc] = f2bf(acc[r][oc]);
        uint4 pk;
        pk.x = (unsigned)ob[0] | ((unsigned)ob[1] << 16);
        pk.y = (unsigned)ob[2] | ((unsigned)ob[3] << 16);
        pk.z = (unsigned)ob[4] | ((unsigned)ob[5] << 16);
        pk.w = (unsigned)ob[6] | ((unsigned)ob[7] << 16);
        // z[b][g][h][w][0..7] -- consecutive lanes (w) 16 B apart: coalesced
        *(uint4*)(z + (size_t)(((b * NG + g) * NH + h) * NW + w) * 8) = pk;
    }
}

// ---------------------------------------------------------------- final conv
// MFMA implicit GEMM, T3+T4 counted-vmcnt schedule.
// grid 2048: b = id&7 (XCD pin), j = id>>3, nb = j&1 (oc half), h = j>>1.
// block 256 thr / 4 waves, tile 128 w x 128 oc, wave 64x64.
// 36 sub-steps s = 3k+dw (k = dh*4+kc): consume Bbuf[s%3] (= Bbuf[dw]), Abuf[k&1].
// Staging plan (issued AFTER the sub-step's barrier):
//   sub0(k): B(3k+2)->Bbuf2 ; A(k+1)->Abuf[(k+1)&1]
//   sub1(k): B(3k+3)->Bbuf0
//   sub2(k): B(3k+4)->Bbuf1
// vmcnt before barrier = #loads issued after the newest needed load:
//   sub0: 4 ; sub1: 8 (tail k=11: 4) ; sub2: 8 (tail k=11: 0).
// Safety: each buffer overwrite happens after a barrier whose arrivals all did
// `s_waitcnt lgkmcnt(0)` -> every wave's ds_reads of that buffer completed.
// LDS = A 2x16 KB + B 3x16 KB = 80 KB -> 2 blocks/CU.
__global__ __launch_bounds__(256) void final_k(const unsigned short* __restrict__ z,
                                               const unsigned short* __restrict__ wtT,
                                               const float* __restrict__ cb,
                                               float* __restrict__ out) {
    __shared__ s16x8 sAv[2][1024];     // A dbuf: 128 w x 8 gq chunks, XOR-swizzled
    __shared__ s16x8 sBv[3][1024];     // B triple-buffer

    const int id = blockIdx.x;
    const int b  = id & 7;
    const int jb = id >> 3;
    const int nb = jb & 1;
    const int h  = jb >> 1;

    const int tid  = threadIdx.x;
    const int wv   = tid >> 6;
    const int lane = tid & 63;
    const int l15  = lane & 15;
    const int quad = lane >> 4;
    const int mo   = (wv & 1) << 6;          // w offset of wave tile
    const int nol  = (wv >> 1) << 6;         // oc offset within 128-oc block tile
    const int n0   = (nb << 7) + nol;        // global oc base of wave tile

    // A staging: LDS chunk ch = w*8 + s holds plane gq = s ^ (w&7), bytes w*16.
    // Source pre-swizzled; dest linear (wave-uniform base + lane*16). Proven r2-r4.
    int srcA[4], ldsoff[4];
#pragma unroll
    for (int it = 0; it < 4; ++it) {
        int ch = it * 256 + tid;
        int w_ = ch >> 3, s = ch & 7;
        int gq = s ^ (w_ & 7);
        srcA[it]   = gq * 262144 + w_ * 16;  // plane (g) stride 256 KB
        ldsoff[it] = it * 256 + wv * 64;     // chunk index of wave's uniform base
    }
    // B staging: wtT rows of 512 B, swizzled cols. Proven r0/r1.
    int srcB[4];
#pragma unroll
    for (int it = 0; it < 4; ++it) {
        int ch  = it * 256 + tid;
        int row = ch >> 3, cp = ch & 7;
        srcB[it] = row * 512 + ((cp ^ (row & 7)) << 4);
    }

    // A read offsets (0-conflict pattern)
    int aoff[3][4][2];
#pragma unroll
    for (int dw = 0; dw < 3; ++dw)
#pragma unroll
        for (int i = 0; i < 4; ++i) {
            int w_ = refl128(mo + 16 * i + l15 + dw - 1);
#pragma unroll
            for (int kk = 0; kk < 2; ++kk) {
                int gq = kk * 4 + quad;
                aoff[dw][i][kk] = w_ * 8 + (gq ^ (w_ & 7));
            }
        }
    int boff[4][2];
#pragma unroll
    for (int j = 0; j < 4; ++j) {
        int oc_l = nol + 16 * j + l15;
#pragma unroll
        for (int kk = 0; kk < 2; ++kk)
            boff[j][kk] = oc_l * 8 + ((kk * 4 + quad) ^ (oc_l & 7));
    }

    const char* zb = (const char*)z + (size_t)b * (NG * NH * NW * CPG * 2);  // 8 MB/image
    const char* zr[3];
#pragma unroll
    for (int dh = 0; dh < 3; ++dh)
        zr[dh] = zb + (size_t)refl128(h + dh - 1) * (NW * CPG * 2);          // 2 KB/row seg
    const char* wt = (const char*)wtT + nb * 65536;    // oc-half base; tap stride 131072

    auto stageA = [&](int k, int sel) {      // A(k): rows for dh=k>>2, g-block kc=k&3
        const char* g = zr[k >> 2] + (size_t)(k & 3) * 2097152;
#pragma unroll
        for (int it = 0; it < 4; ++it)
            async_load16(g + srcA[it], (void*)(sAv[sel] + ldsoff[it]));
    };
    auto stageB = [&](int tap, int kc, int bsel) {   // B slab for one tap, 64-ch chunk
        const char* g = wt + (size_t)tap * 131072 + kc * 128;
#pragma unroll
        for (int it = 0; it < 4; ++it)
            async_load16(g + srcB[it], (void*)(sBv[bsel] + ldsoff[it]));
    };

    f32x4 acc[4][4] = {};

    auto compute = [&](const int (&ao)[4][2], int bsel, int asel) {
        const s16x8* abase = sAv[asel];
        const s16x8* bbase = sBv[bsel];
        __builtin_amdgcn_s_setprio(1);
#pragma unroll
        for (int kk = 0; kk < 2; ++kk) {
            s16x8 av[4], bv[4];
#pragma unroll
            for (int i = 0; i < 4; ++i) av[i] = abase[ao[i][kk]];
#pragma unroll
            for (int j = 0; j < 4; ++j) bv[j] = bbase[boff[j][kk]];
#pragma unroll
            for (int i = 0; i < 4; ++i)
#pragma unroll
                for (int j = 0; j < 4; ++j)
                    acc[i][j] = __builtin_amdgcn_mfma_f32_16x16x32_bf16(
                        av[i], bv[j], acc[i][j], 0, 0, 0);
        }
        __builtin_amdgcn_s_setprio(0);
    };

#define WAITB(N)                                                        \
    asm volatile("s_waitcnt vmcnt(" #N ") lgkmcnt(0)" ::: "memory");    \
    __builtin_amdgcn_sched_barrier(0);                                  \
    __builtin_amdgcn_s_barrier();                                       \
    __builtin_amdgcn_sched_barrier(0);

    // prologue: B(0)->Bbuf0, A(0)->Abuf0, B(1)->Bbuf1  (12 loads/thread)
    stageB(0, 0, 0);
    stageA(0, 0);
    stageB(1, 0, 1);

    for (int k = 0; k < 12; ++k) {
        const int dh = k >> 2, kc = k & 3;
        const int asel = k & 1;
        const int kn = k + 1;
        const int dhn = kn >> 2, kcn = kn & 3;   // next k (valid when k<11)

        // ---- sub0: dw=0, consumes Bbuf0, Abuf[asel]
        WAITB(4)
        stageB(dh * 3 + 2, kc, 2);               // B(3k+2) -> Bbuf2
        if (k < 11) stageA(kn, asel ^ 1);        // A(k+1)
        compute(aoff[0], 0, asel);

        // ---- sub1: dw=1, consumes Bbuf1
        if (k < 11) { WAITB(8) } else { WAITB(4) }
        if (k < 11) stageB(dhn * 3, kcn, 0);     // B(3k+3) -> Bbuf0
        compute(aoff[1], 1, asel);

        // ---- sub2: dw=2, consumes Bbuf2
        if (k < 11) { WAITB(8) } else { WAITB(0) }
        if (k < 11) stageB(dhn * 3 + 1, kcn, 1); // B(3k+4) -> Bbuf1
        compute(aoff[2], 2, asel);
    }
#undef WAITB

    // epilogue: D layout col=lane&15 (oc), row=quad*4+reg (w)
#pragma unroll
    for (int j = 0; j < 4; ++j) {
        int oc = n0 + 16 * j + l15;
        float bvl = cb[oc];
#pragma unroll
        for (int i = 0; i < 4; ++i) {
            int w0 = mo + 16 * i + quad * 4;
            float* dst = out + (((size_t)(b * NOUT + oc) * NH + h) * NW + w0);
            f32x4 v = acc[i][j];
            float4 o4 = { v[0] + bvl, v[1] + bvl, v[2] + bvl, v[3] + bvl };
            *(float4*)dst = o4;
        }
    }
}

// ---------------------------------------------------------------- launch
extern "C" void kernel_launch(void* const* d_in, const int* in_sizes, int n_in,
                              void* d_out, int out_size, void* d_ws, size_t ws_size,
                              hipStream_t stream) {
    const float* x   = (const float*)d_in[0];
    const float* wsp = (const float*)d_in[1];
    const float* wpw = (const float*)d_in[2];
    const float* bia = (const float*)d_in[3];
    const float* cw  = (const float*)d_in[4];
    const float* cb  = (const float*)d_in[5];
    float* out = (float*)d_out;

    // workspace layout (16B aligned):
    //   stats 16 KB | weff 576 KB | wtT 1.13 MB | z 64 MB
    char* ws = (char*)d_ws;
    float*          stats = (float*)ws;                          // 2048*2 f32
    float*          weff  = (float*)(ws + 16384);                // 2048*72 f32
    unsigned short* wtT   = (unsigned short*)(ws + 606208);      // 9*256*256 bf16
    unsigned short* z     = (unsigned short*)(ws + 1785856);     // [8][32][128][128][8] bf16

    stats_k <<<NB * NC, 256, 0, stream>>>(x, stats);
    weff_k  <<<576,     256, 0, stream>>>(wsp, wpw, weff);
    repack_k<<<2304,    256, 0, stream>>>(cw, wtT);
    ada_k   <<<NB * NG * (NH / 8), 256, 0, stream>>>(x, stats, weff, bia, z);
    final_k <<<NB * NH * 2,  256, 0, stream>>>(z, wtT, cb, out);
}

// Round 6
// 447.882 us; speedup vs baseline: 1.3935x; 1.0036x over previous
//
#include <hip/hip_runtime.h>
#include <stdint.h>
#include <stddef.h>

// Problem: AdaConv2d  B=8 C=256 H=W=128 G=32 CPG=8 K=3 OUT=256
// Pipeline: instance-norm -> per-sample adaptive grouped 3x3 (+1x1 grouped +bias)
//           -> static 3x3 conv 256->256, reflect padding everywhere.
//
// z intermediate layout: [B][G][H][W][8] bf16 (group-blocked channels-last).
// ada conv  = MFMA implicit GEMM per (b,g): out[oc 8][pix] = W[72][8]^T X[72][pix],
//   K padded to 96 (3x mfma 16x16x32), oc on M (8/16 rows), pixels on N.
//   k-order = tap*8+ic -> B-frag = one channels-last 16B LDS slot (1 ds_read_b128).
//   W-frags precomputed in fragment layout by wfrag_k. xn quantized to bf16.
// final conv = bf16 MFMA implicit GEMM, R0 schedule (A single + B dbuf, 48 KB,
//   3 blocks/CU) with R2's 0-conflict A swizzle: chunk = w*8 + (gq ^ (w&7)).

typedef __attribute__((ext_vector_type(8))) short   s16x8;  // 8 bf16 in 4 VGPRs
typedef __attribute__((ext_vector_type(4))) float   f32x4;

#define NB   8
#define NC   256
#define NH   128
#define NW   128
#define NG   32
#define CPG  8
#define NOUT 256
#define HWPLANE (NH*NW)          // 16384

__device__ __forceinline__ unsigned short f2bf(float f) {
    union { float f; unsigned u; } v; v.f = f;
    unsigned u = v.u;
    u += 0x7fffu + ((u >> 16) & 1u);   // RNE
    return (unsigned short)(u >> 16);
}

__device__ __forceinline__ int refl128(int i) {
    return i < 0 ? 1 : (i > 127 ? 126 : i);
}

__device__ __forceinline__ void async_load16(const void* g, void* l) {
    __builtin_amdgcn_global_load_lds(
        (const __attribute__((address_space(1))) unsigned int*)g,
        (__attribute__((address_space(3))) unsigned int*)l,
        16, 0, 0);
}

// ---------------------------------------------------------------- stats
__global__ __launch_bounds__(256) void stats_k(const float* __restrict__ x,
                                               float* __restrict__ stats) {
    int bc = blockIdx.x, t = threadIdx.x;
    const float4* p = (const float4*)(x + (size_t)bc * HWPLANE);
    float s = 0.f, q = 0.f;
#pragma unroll
    for (int k = 0; k < 16; ++k) {
        float4 v = p[k * 256 + t];
        s += v.x + v.y + v.z + v.w;
        q += v.x * v.x + v.y * v.y + v.z * v.z + v.w * v.w;
    }
    __shared__ float ss[256], sq[256];
    ss[t] = s; sq[t] = q;
    __syncthreads();
    for (int o = 128; o > 0; o >>= 1) {
        if (t < o) { ss[t] += ss[t + o]; sq[t] += sq[t + o]; }
        __syncthreads();
    }
    if (t == 0) {
        float mean = ss[0] * (1.f / HWPLANE);
        float var  = sq[0] * (1.f / HWPLANE) - mean * mean;
        stats[bc * 2]     = mean;
        stats[bc * 2 + 1] = rsqrtf(var + 1e-5f);
    }
}

// ---------------------------------------------------------------- wfrag
// W MFMA A-fragments (M=oc, K=tap*8+ic, padded to 96) + padded bias.
// A-frag layout (mfma_f32_16x16x32_bf16): lane l holds A[row=l&15][k=(l>>4)*8+e].
// wfrag[bg][kw][lane][e] = weff(bg, ic=e, tap=kw*4+(l>>4), oc=l&15), 0 if tap>8|oc>7
// weff(bg,ic,tap,oc) = sum_j wpw[(bg*8+oc)*8+j] * wsp[((bg*8+j)*8+ic)*9+tap]
// bias16[bg][16]: bias padded with zeros for oc 8..15.
__global__ __launch_bounds__(256) void wfrag_k(const float* __restrict__ wsp,
                                               const float* __restrict__ wpw,
                                               const float* __restrict__ bias,
                                               unsigned short* __restrict__ wfrag,
                                               float* __restrict__ bias16) {
    int tid = blockIdx.x * 256 + threadIdx.x;   // 53248 total (208 blocks)
    if (tid < 49152) {
        int lane = tid & 63;
        int kw   = (tid >> 6) % 3;
        int bg   = tid / 192;
        int oc   = lane & 15;
        int tap  = kw * 4 + (lane >> 4);
        unsigned short fr[8];
#pragma unroll
        for (int e = 0; e < 8; ++e) {
            float v = 0.f;
            if (tap < 9 && oc < 8) {
#pragma unroll
                for (int j = 0; j < 8; ++j)
                    v += wpw[(bg * 8 + oc) * 8 + j] *
                         wsp[((bg * 8 + j) * 8 + e) * 9 + tap];
            }
            fr[e] = f2bf(v);
        }
        uint4 pk;
        pk.x = (unsigned)fr[0] | ((unsigned)fr[1] << 16);
        pk.y = (unsigned)fr[2] | ((unsigned)fr[3] << 16);
        pk.z = (unsigned)fr[4] | ((unsigned)fr[5] << 16);
        pk.w = (unsigned)fr[6] | ((unsigned)fr[7] << 16);
        *(uint4*)(wfrag + (size_t)((bg * 3 + kw) * 64 + lane) * 8) = pk;
    } else {
        int t2 = tid - 49152;                    // 0..4095
        int bg = t2 >> 4, j = t2 & 15;
        bias16[bg * 16 + j] = (j < 8) ? bias[bg * 8 + j] : 0.f;
    }
}

// ---------------------------------------------------------------- weight repack
// conv_w [O][C][3][3] fp32  ->  wtT [tap][O][C] bf16
__global__ __launch_bounds__(256) void repack_k(const float* __restrict__ cw,
                                                unsigned short* __restrict__ wtT) {
    int tid = blockIdx.x * 256 + threadIdx.x;           // 589824 total, exact
    int c = tid & 255;
    int o = (tid >> 8) & 255;
    int t = tid >> 16;                                  // 0..8
    float v = cw[(size_t)(o * NC + c) * 9 + t];
    wtT[((size_t)t * NOUT + o) * NC + c] = f2bf(v);
}

// ---------------------------------------------------------------- adaptive conv (MFMA)
// block = (b, g, q 0..3): 256 thr / 4 waves, output rows h0=q*32 .. +31.
// LDS tile [34 rows][128 w][8 ic] bf16 (68 KB): normalized input, channels-last.
// Staging: per (row,w) slot, 8 strided-coalesced dword loads (one per ic) ->
//   normalize fp32 -> pack 8 bf16 -> one b128 LDS write (lane-consec slots).
// Compute: per 16-pixel block, 3x { ds_read_b128 (X frag) + mfma(Wfrag, Xfrag) }.
// C/D: col=lane&15=pixel, row=(lane>>4)*4+reg=oc -> lanes<32 store uint2 coalesced.
__global__ __launch_bounds__(256) void ada_k(const float* __restrict__ x,
                                             const float* __restrict__ stats,
                                             const unsigned short* __restrict__ wfrag,
                                             const float* __restrict__ bias16,
                                             unsigned short* __restrict__ z) {
    __shared__ s16x8 tile[34 * 128];        // 68 KB
    const int id = blockIdx.x;
    const int b  = id & 7;                  // XCD pin
    const int g  = (id >> 3) & 31;
    const int q  = id >> 8;
    const int bg = b * 32 + g;
    const int h0 = q * 32;

    const int tid  = threadIdx.x;
    const int lane = tid & 63;
    const int wv   = tid >> 6;
    const int l15  = lane & 15;
    const int quad = lane >> 4;

    float mean[8], rstd[8];
#pragma unroll
    for (int ic = 0; ic < 8; ++ic) {
        mean[ic] = stats[(bg * 8 + ic) * 2];
        rstd[ic] = stats[(bg * 8 + ic) * 2 + 1];
    }

    const float* xg = x + (size_t)bg * 8 * HWPLANE;
#pragma unroll
    for (int it = 0; it < 17; ++it) {
        int slot = it * 256 + tid;          // 0..4351
        int row  = slot >> 7;
        int w    = slot & 127;
        int gr   = refl128(h0 - 1 + row);
        const float* xp = xg + gr * NW + w;
        unsigned short u[8];
#pragma unroll
        for (int ic = 0; ic < 8; ++ic)
            u[ic] = f2bf((xp[(size_t)ic * HWPLANE] - mean[ic]) * rstd[ic]);
        uint4 pk;
        pk.x = (unsigned)u[0] | ((unsigned)u[1] << 16);
        pk.y = (unsigned)u[2] | ((unsigned)u[3] << 16);
        pk.z = (unsigned)u[4] | ((unsigned)u[5] << 16);
        pk.w = (unsigned)u[6] | ((unsigned)u[7] << 16);
        *(uint4*)&tile[slot] = pk;
    }
    __syncthreads();

    // W fragments + bias (fragment-layout precomputed)
    s16x8 wf[3];
#pragma unroll
    for (int kw = 0; kw < 3; ++kw)
        wf[kw] = *(const s16x8*)(wfrag + (size_t)((bg * 3 + kw) * 64 + lane) * 8);
    float4 bv = *(const float4*)(bias16 + bg * 16 + quad * 4);

    // per-lane tap geometry: tap = kw*4 + quad
    int dhA[3], dwm[3];
#pragma unroll
    for (int kw = 0; kw < 3; ++kw) {
        int tap = kw * 4 + quad;
        if (tap < 9) { dhA[kw] = tap / 3; dwm[kw] = tap % 3 - 1; }
        else         { dhA[kw] = 0;       dwm[kw] = 0; }        // zero W-frag
    }

#pragma unroll 2
    for (int i = 0; i < 64; ++i) {
        int pb = wv * 64 + i;               // pixel block: 16 pixels
        int ro = pb >> 3;                   // 0..31 output row in tile
        int w0 = (pb & 7) * 16;
        f32x4 acc = {};
#pragma unroll
        for (int kw = 0; kw < 3; ++kw) {
            int wr = refl128(w0 + l15 + dwm[kw]);
            s16x8 xf = tile[(ro + dhA[kw]) * 128 + wr];
            acc = __builtin_amdgcn_mfma_f32_16x16x32_bf16(wf[kw], xf, acc, 0, 0, 0);
        }
        unsigned short o0 = f2bf(acc[0] + bv.x);
        unsigned short o1 = f2bf(acc[1] + bv.y);
        unsigned short o2 = f2bf(acc[2] + bv.z);
        unsigned short o3 = f2bf(acc[3] + bv.w);
        if (lane < 32) {
            uint2 pk2 = { (unsigned)o0 | ((unsigned)o1 << 16),
                          (unsigned)o2 | ((unsigned)o3 << 16) };
            unsigned short* zp = z + ((size_t)(bg * NH + h0 + ro) * NW + w0 + l15) * 8
                                   + quad * 4;
            *(uint2*)zp = pk2;
        }
    }
}

// ---------------------------------------------------------------- final conv (LDS-tiled MFMA implicit GEMM)
// grid 2048: b = id&7 (XCD pin), j = id>>3, nb = j&1 (oc half), h = j>>1.
// block 256 thr / 4 waves, tile 128 w x 128 oc, wave 64x64, BK=64.
// LDS: A 16 KB (single) + B 2x16 KB (dbuf) = 48 KB -> 3 blocks/CU.
// A LDS chunk = w*8 + (gq ^ (w&7)) (0-conflict), via pre-swizzled global source.
__global__ __launch_bounds__(256) void final_k(const unsigned short* __restrict__ z,
                                               const unsigned short* __restrict__ wtT,
                                               const float* __restrict__ cb,
                                               float* __restrict__ out) {
    __shared__ s16x8 sAv[1024];        // 128 w x 8 gq chunks (16 B), XOR-swizzled
    __shared__ s16x8 sBv[2][1024];

    const int id = blockIdx.x;
    const int b  = id & 7;
    const int jb = id >> 3;
    const int nb = jb & 1;
    const int h  = jb >> 1;

    const int tid  = threadIdx.x;
    const int wv   = tid >> 6;
    const int lane = tid & 63;
    const int l15  = lane & 15;
    const int quad = lane >> 4;
    const int mo   = (wv & 1) << 6;          // w offset of wave tile
    const int nol  = (wv >> 1) << 6;         // oc offset within 128-oc block tile
    const int n0   = (nb << 7) + nol;        // global oc base of wave tile

    // A staging: LDS chunk ch = w*8 + s holds plane gq = s ^ (w&7), bytes w*16.
    int srcA[4], ldsoff[4];
#pragma unroll
    for (int it = 0; it < 4; ++it) {
        int ch = it * 256 + tid;
        int w_ = ch >> 3, s = ch & 7;
        int gq = s ^ (w_ & 7);
        srcA[it]   = gq * 262144 + w_ * 16;  // plane (g) stride 256 KB
        ldsoff[it] = it * 256 + wv * 64;     // chunk index of wave's uniform base
    }
    // B staging: wtT rows of 512 B, swizzled cols.
    int srcB[4];
#pragma unroll
    for (int it = 0; it < 4; ++it) {
        int ch  = it * 256 + tid;
        int row = ch >> 3, cp = ch & 7;
        srcB[it] = row * 512 + ((cp ^ (row & 7)) << 4);
    }

    // A read offsets (0-conflict pattern)
    int aoff[3][4][2];
#pragma unroll
    for (int dw = 0; dw < 3; ++dw)
#pragma unroll
        for (int i = 0; i < 4; ++i) {
            int w_ = refl128(mo + 16 * i + l15 + dw - 1);
#pragma unroll
            for (int kk = 0; kk < 2; ++kk) {
                int gq = kk * 4 + quad;
                aoff[dw][i][kk] = w_ * 8 + (gq ^ (w_ & 7));
            }
        }
    int boff[4][2];
#pragma unroll
    for (int j = 0; j < 4; ++j) {
        int oc_l = nol + 16 * j + l15;
#pragma unroll
        for (int kk = 0; kk < 2; ++kk)
            boff[j][kk] = oc_l * 8 + ((kk * 4 + quad) ^ (oc_l & 7));
    }

    const char* zb = (const char*)z + (size_t)b * (NG * NH * NW * CPG * 2);  // 8 MB/image
    const char* zr[3];
#pragma unroll
    for (int dh = 0; dh < 3; ++dh)
        zr[dh] = zb + (size_t)refl128(h + dh - 1) * (NW * CPG * 2);          // 2 KB/row seg
    const char* wt = (const char*)wtT + nb * 65536;    // oc-half base; tap stride 131072

    auto stageA = [&](const char* g) {
#pragma unroll
        for (int it = 0; it < 4; ++it)
            async_load16(g + srcA[it], (void*)(sAv + ldsoff[it]));
    };
    auto stageB = [&](const char* g, int bsel) {
#pragma unroll
        for (int it = 0; it < 4; ++it)
            async_load16(g + srcB[it], (void*)(sBv[bsel] + ldsoff[it]));
    };

    f32x4 acc[4][4] = {};

    auto compute = [&](const int (&ao)[4][2], int bsel) {
        const s16x8* bbase = sBv[bsel];
#pragma unroll
        for (int kk = 0; kk < 2; ++kk) {
            s16x8 av[4], bv[4];
#pragma unroll
            for (int i = 0; i < 4; ++i) av[i] = sAv[ao[i][kk]];
#pragma unroll
            for (int j = 0; j < 4; ++j) bv[j] = bbase[boff[j][kk]];
#pragma unroll
            for (int i = 0; i < 4; ++i)
#pragma unroll
                for (int j = 0; j < 4; ++j)
                    acc[i][j] = __builtin_amdgcn_mfma_f32_16x16x32_bf16(
                        av[i], bv[j], acc[i][j], 0, 0, 0);
        }
    };

    int buf = 0;
    stageA(zr[0]);
    stageB(wt, 0);
    __syncthreads();

    for (int sc = 0; sc < 12; ++sc) {
        const int dh = sc >> 2, kc = sc & 3;
        const char* bt = wt + (size_t)(dh * 3) * 131072 + kc * 128;
        stageB(bt + 131072, buf ^ 1);          // prefetch dw=1
        compute(aoff[0], buf);
        __syncthreads(); buf ^= 1;
        stageB(bt + 262144, buf ^ 1);          // prefetch dw=2
        compute(aoff[1], buf);
        __syncthreads(); buf ^= 1;
        compute(aoff[2], buf);
        __syncthreads();
        if (sc < 11) {                         // stage next (dh,kc): A + first B
            const int sn = sc + 1, dhn = sn >> 2, kcn = sn & 3;
            stageA(zr[dhn] + (size_t)kcn * 2097152);   // kc selects g-block of 8
            stageB(wt + (size_t)(dhn * 3) * 131072 + kcn * 128, buf ^ 1);
            __syncthreads();
        }
        buf ^= 1;
    }

    // epilogue: D layout col=lane&15 (oc), row=quad*4+reg (w)
#pragma unroll
    for (int j = 0; j < 4; ++j) {
        int oc = n0 + 16 * j + l15;
        float bvl = cb[oc];
#pragma unroll
        for (int i = 0; i < 4; ++i) {
            int w0 = mo + 16 * i + quad * 4;
            float* dst = out + (((size_t)(b * NOUT + oc) * NH + h) * NW + w0);
            f32x4 v = acc[i][j];
            float4 o4 = { v[0] + bvl, v[1] + bvl, v[2] + bvl, v[3] + bvl };
            *(float4*)dst = o4;
        }
    }
}

// ---------------------------------------------------------------- launch
extern "C" void kernel_launch(void* const* d_in, const int* in_sizes, int n_in,
                              void* d_out, int out_size, void* d_ws, size_t ws_size,
                              hipStream_t stream) {
    const float* x   = (const float*)d_in[0];
    const float* wsp = (const float*)d_in[1];
    const float* wpw = (const float*)d_in[2];
    const float* bia = (const float*)d_in[3];
    const float* cw  = (const float*)d_in[4];
    const float* cb  = (const float*)d_in[5];
    float* out = (float*)d_out;

    // workspace layout (16B aligned):
    //   stats 16 KB | wfrag 768 KB | bias16 16 KB | wtT 1.13 MB | z 64 MB
    char* ws = (char*)d_ws;
    float*          stats  = (float*)ws;                          // 2048*2 f32
    unsigned short* wfrag  = (unsigned short*)(ws + 16384);       // 256*3*64*8 bf16
    float*          bias16 = (float*)(ws + 802816);               // 256*16 f32
    unsigned short* wtT    = (unsigned short*)(ws + 819200);      // 9*256*256 bf16
    unsigned short* z      = (unsigned short*)(ws + 1998848);     // [8][32][128][128][8]

    stats_k <<<NB * NC, 256, 0, stream>>>(x, stats);
    wfrag_k <<<208,     256, 0, stream>>>(wsp, wpw, bia, wfrag, bias16);
    repack_k<<<2304,    256, 0, stream>>>(cw, wtT);
    ada_k   <<<NB * NG * 4, 256, 0, stream>>>(x, stats, wfrag, bias16, z);
    final_k <<<NB * NH * 2, 256, 0, stream>>>(z, wtT, cb, out);
}

// Round 7
// 438.324 us; speedup vs baseline: 1.4239x; 1.0218x over previous
//
#include <hip/hip_runtime.h>
#include <stdint.h>
#include <stddef.h>

// Problem: AdaConv2d  B=8 C=256 H=W=128 G=32 CPG=8 K=3 OUT=256
// Pipeline: instance-norm -> per-sample adaptive grouped 3x3 (+1x1 grouped +bias)
//           -> static 3x3 conv 256->256, reflect padding everywhere.
//
// z intermediate layout: [B][G][H][W][8] bf16 (group-blocked channels-last).
// ada conv  = MFMA implicit GEMM per (b,g): out[oc 8][pix] = W[72][8]^T X[72][pix],
//   K padded to 96 (3x mfma 16x16x32), oc on M (8/16 rows), pixels on N.
// final conv = bf16 MFMA implicit GEMM, R1 structure (proven 143 us):
//   A single-buffered + B double-buffered, 48 KB LDS -> 3 blocks/CU;
//   A staged with DENSE per-plane global_load_lds sources (1 KB/wave contiguous)
//   -- dense staging sources beat "0-conflict" reads (R5/R6 scatter cost ~45 us;
//   the 6.3M read-conflict counter costs ~2.5 us total, benign).

typedef __attribute__((ext_vector_type(8))) short   s16x8;  // 8 bf16 in 4 VGPRs
typedef __attribute__((ext_vector_type(4))) float   f32x4;

#define NB   8
#define NC   256
#define NH   128
#define NW   128
#define NG   32
#define CPG  8
#define NOUT 256
#define HWPLANE (NH*NW)          // 16384

__device__ __forceinline__ unsigned short f2bf(float f) {
    union { float f; unsigned u; } v; v.f = f;
    unsigned u = v.u;
    u += 0x7fffu + ((u >> 16) & 1u);   // RNE
    return (unsigned short)(u >> 16);
}

__device__ __forceinline__ int refl128(int i) {
    return i < 0 ? 1 : (i > 127 ? 126 : i);
}

__device__ __forceinline__ void async_load16(const void* g, void* l) {
    __builtin_amdgcn_global_load_lds(
        (const __attribute__((address_space(1))) unsigned int*)g,
        (__attribute__((address_space(3))) unsigned int*)l,
        16, 0, 0);
}

// ---------------------------------------------------------------- stats
__global__ __launch_bounds__(256) void stats_k(const float* __restrict__ x,
                                               float* __restrict__ stats) {
    int bc = blockIdx.x, t = threadIdx.x;
    const float4* p = (const float4*)(x + (size_t)bc * HWPLANE);
    float s = 0.f, q = 0.f;
#pragma unroll
    for (int k = 0; k < 16; ++k) {
        float4 v = p[k * 256 + t];
        s += v.x + v.y + v.z + v.w;
        q += v.x * v.x + v.y * v.y + v.z * v.z + v.w * v.w;
    }
    __shared__ float ss[256], sq[256];
    ss[t] = s; sq[t] = q;
    __syncthreads();
    for (int o = 128; o > 0; o >>= 1) {
        if (t < o) { ss[t] += ss[t + o]; sq[t] += sq[t + o]; }
        __syncthreads();
    }
    if (t == 0) {
        float mean = ss[0] * (1.f / HWPLANE);
        float var  = sq[0] * (1.f / HWPLANE) - mean * mean;
        stats[bc * 2]     = mean;
        stats[bc * 2 + 1] = rsqrtf(var + 1e-5f);
    }
}

// ---------------------------------------------------------------- wfrag
// W MFMA A-fragments (M=oc, K=tap*8+ic, padded to 96) + padded bias.
// A-frag layout (mfma_f32_16x16x32_bf16): lane l holds A[row=l&15][k=(l>>4)*8+e].
// wfrag[bg][kw][lane][e] = weff(bg, ic=e, tap=kw*4+(l>>4), oc=l&15), 0 if tap>8|oc>7
// weff(bg,ic,tap,oc) = sum_j wpw[(bg*8+oc)*8+j] * wsp[((bg*8+j)*8+ic)*9+tap]
// bias16[bg][16]: bias padded with zeros for oc 8..15.
__global__ __launch_bounds__(256) void wfrag_k(const float* __restrict__ wsp,
                                               const float* __restrict__ wpw,
                                               const float* __restrict__ bias,
                                               unsigned short* __restrict__ wfrag,
                                               float* __restrict__ bias16) {
    int tid = blockIdx.x * 256 + threadIdx.x;   // 53248 total (208 blocks)
    if (tid < 49152) {
        int lane = tid & 63;
        int kw   = (tid >> 6) % 3;
        int bg   = tid / 192;
        int oc   = lane & 15;
        int tap  = kw * 4 + (lane >> 4);
        unsigned short fr[8];
#pragma unroll
        for (int e = 0; e < 8; ++e) {
            float v = 0.f;
            if (tap < 9 && oc < 8) {
#pragma unroll
                for (int j = 0; j < 8; ++j)
                    v += wpw[(bg * 8 + oc) * 8 + j] *
                         wsp[((bg * 8 + j) * 8 + e) * 9 + tap];
            }
            fr[e] = f2bf(v);
        }
        uint4 pk;
        pk.x = (unsigned)fr[0] | ((unsigned)fr[1] << 16);
        pk.y = (unsigned)fr[2] | ((unsigned)fr[3] << 16);
        pk.z = (unsigned)fr[4] | ((unsigned)fr[5] << 16);
        pk.w = (unsigned)fr[6] | ((unsigned)fr[7] << 16);
        *(uint4*)(wfrag + (size_t)((bg * 3 + kw) * 64 + lane) * 8) = pk;
    } else {
        int t2 = tid - 49152;                    // 0..4095
        int bg = t2 >> 4, j = t2 & 15;
        bias16[bg * 16 + j] = (j < 8) ? bias[bg * 8 + j] : 0.f;
    }
}

// ---------------------------------------------------------------- weight repack
// conv_w [O][C][3][3] fp32 -> wtT [tap][O][C] bf16, via LDS transpose:
// block stages 2304 consecutive floats (256 (o,c) pairs x 9 taps) coalesced,
// then writes per-tap runs of 256 consecutive bf16 (128 B/wave contiguous).
__global__ __launch_bounds__(256) void repack_k(const float* __restrict__ cw,
                                                unsigned short* __restrict__ wtT) {
    __shared__ float ld[2304];
    const int blk = blockIdx.x;                 // 256 blocks
    const float* src = cw + (size_t)blk * 2304;
#pragma unroll
    for (int it = 0; it < 9; ++it)
        ld[it * 256 + threadIdx.x] = src[it * 256 + threadIdx.x];
    __syncthreads();
    int p = blk * 256 + threadIdx.x;            // (o,c) pair index
    int o = p >> 8, c = p & 255;
#pragma unroll
    for (int t = 0; t < 9; ++t)
        wtT[((size_t)t * NOUT + o) * NC + c] = f2bf(ld[threadIdx.x * 9 + t]);
}

// ---------------------------------------------------------------- adaptive conv (MFMA)
// block = (b, g, q 0..3): 256 thr / 4 waves, output rows h0=q*32 .. +31.
// LDS tile [34 rows][128 w][8 ic] bf16 (68 KB): normalized input, channels-last.
// Staging: per (row,w) slot, 8 strided-coalesced dword loads (one per ic) ->
//   normalize fp32 -> pack 8 bf16 -> one b128 LDS write (lane-consec slots).
// Compute: per 16-pixel block, 3x { ds_read_b128 (X frag) + mfma(Wfrag, Xfrag) }.
// C/D: col=lane&15=pixel, row=(lane>>4)*4+reg=oc -> lanes<32 store uint2 coalesced.
__global__ __launch_bounds__(256) void ada_k(const float* __restrict__ x,
                                             const float* __restrict__ stats,
                                             const unsigned short* __restrict__ wfrag,
                                             const float* __restrict__ bias16,
                                             unsigned short* __restrict__ z) {
    __shared__ s16x8 tile[34 * 128];        // 68 KB
    const int id = blockIdx.x;
    const int b  = id & 7;                  // XCD pin
    const int g  = (id >> 3) & 31;
    const int q  = id >> 8;
    const int bg = b * 32 + g;
    const int h0 = q * 32;

    const int tid  = threadIdx.x;
    const int lane = tid & 63;
    const int wv   = tid >> 6;
    const int l15  = lane & 15;
    const int quad = lane >> 4;

    float mean[8], rstd[8];
#pragma unroll
    for (int ic = 0; ic < 8; ++ic) {
        mean[ic] = stats[(bg * 8 + ic) * 2];
        rstd[ic] = stats[(bg * 8 + ic) * 2 + 1];
    }

    const float* xg = x + (size_t)bg * 8 * HWPLANE;
#pragma unroll
    for (int it = 0; it < 17; ++it) {
        int slot = it * 256 + tid;          // 0..4351
        int row  = slot >> 7;
        int w    = slot & 127;
        int gr   = refl128(h0 - 1 + row);
        const float* xp = xg + gr * NW + w;
        unsigned short u[8];
#pragma unroll
        for (int ic = 0; ic < 8; ++ic)
            u[ic] = f2bf((xp[(size_t)ic * HWPLANE] - mean[ic]) * rstd[ic]);
        uint4 pk;
        pk.x = (unsigned)u[0] | ((unsigned)u[1] << 16);
        pk.y = (unsigned)u[2] | ((unsigned)u[3] << 16);
        pk.z = (unsigned)u[4] | ((unsigned)u[5] << 16);
        pk.w = (unsigned)u[6] | ((unsigned)u[7] << 16);
        *(uint4*)&tile[slot] = pk;
    }
    __syncthreads();

    // W fragments + bias (fragment-layout precomputed)
    s16x8 wf[3];
#pragma unroll
    for (int kw = 0; kw < 3; ++kw)
        wf[kw] = *(const s16x8*)(wfrag + (size_t)((bg * 3 + kw) * 64 + lane) * 8);
    float4 bv = *(const float4*)(bias16 + bg * 16 + quad * 4);

    // per-lane tap geometry: tap = kw*4 + quad
    int dhA[3], dwm[3];
#pragma unroll
    for (int kw = 0; kw < 3; ++kw) {
        int tap = kw * 4 + quad;
        if (tap < 9) { dhA[kw] = tap / 3; dwm[kw] = tap % 3 - 1; }
        else         { dhA[kw] = 0;       dwm[kw] = 0; }        // zero W-frag
    }

#pragma unroll 2
    for (int i = 0; i < 64; ++i) {
        int pb = wv * 64 + i;               // pixel block: 16 pixels
        int ro = pb >> 3;                   // 0..31 output row in tile
        int w0 = (pb & 7) * 16;
        f32x4 acc = {};
#pragma unroll
        for (int kw = 0; kw < 3; ++kw) {
            int wr = refl128(w0 + l15 + dwm[kw]);
            s16x8 xf = tile[(ro + dhA[kw]) * 128 + wr];
            acc = __builtin_amdgcn_mfma_f32_16x16x32_bf16(wf[kw], xf, acc, 0, 0, 0);
        }
        unsigned short o0 = f2bf(acc[0] + bv.x);
        unsigned short o1 = f2bf(acc[1] + bv.y);
        unsigned short o2 = f2bf(acc[2] + bv.z);
        unsigned short o3 = f2bf(acc[3] + bv.w);
        if (lane < 32) {
            uint2 pk2 = { (unsigned)o0 | ((unsigned)o1 << 16),
                          (unsigned)o2 | ((unsigned)o3 << 16) };
            unsigned short* zp = z + ((size_t)(bg * NH + h0 + ro) * NW + w0 + l15) * 8
                                   + quad * 4;
            *(uint2*)zp = pk2;
        }
    }
}

// ---------------------------------------------------------------- final conv (LDS-tiled MFMA implicit GEMM)
// R1 version verbatim (measured 141-143 us on this z layout).
// grid 2048: b = id&7 (XCD pin), j = id>>3, nb = j&1 (oc half), h = j>>1.
// block 256 thr / 4 waves, tile 128 w x 128 oc, wave 64x64, BK=64.
// LDS: A 16 KB (single) + B 2x16 KB (dbuf) = 48 KB -> 3 blocks/CU.
// A LDS layout: chunk = gq*128 + (w ^ (gq&7)); staged with DENSE per-plane
// sources (per wave: 64 consecutive swizzled slots within one plane's 2 KB row).
__global__ __launch_bounds__(256) void final_k(const unsigned short* __restrict__ z,
                                               const unsigned short* __restrict__ wtT,
                                               const float* __restrict__ cb,
                                               float* __restrict__ out) {
    __shared__ s16x8 sAv[1024];        // 8 gq x 128 w chunks (16 B), XOR-swizzled
    __shared__ s16x8 sBv[2][1024];

    const int id = blockIdx.x;
    const int b  = id & 7;
    const int jb = id >> 3;
    const int nb = jb & 1;
    const int h  = jb >> 1;

    const int tid  = threadIdx.x;
    const int wv   = tid >> 6;
    const int lane = tid & 63;
    const int l15  = lane & 15;
    const int quad = lane >> 4;
    const int mo   = (wv & 1) << 6;          // w offset of wave tile
    const int nol  = (wv >> 1) << 6;         // oc offset within 128-oc block tile
    const int n0   = (nb << 7) + nol;        // global oc base of wave tile

    // B staging (wtT [tap][o][c], o-major rows of 512 B): per-lane swizzled source
    int srcB[4], ldsoff[4];
#pragma unroll
    for (int it = 0; it < 4; ++it) {
        int ch  = it * 256 + tid;
        int row = ch >> 3, cp = ch & 7;
        srcB[it]   = row * 512 + ((cp ^ (row & 7)) << 4);
        ldsoff[it] = it * 256 + wv * 64;     // chunk index of wave's uniform base
    }

    // A staging (z [g][h][w][8]): chunk = gq*128 + wslot holds global w = wslot^(gq&7)
    int srcA[4];
#pragma unroll
    for (int it = 0; it < 4; ++it) {
        int ch = it * 256 + tid;
        int gq = ch >> 7, wslot = ch & 127;
        srcA[it] = gq * 262144 + ((wslot ^ (gq & 7)) << 4);   // g stride 256 KB
    }

    int aoff[3][4][2];
#pragma unroll
    for (int dw = 0; dw < 3; ++dw)
#pragma unroll
        for (int i = 0; i < 4; ++i) {
            int w_ = refl128(mo + 16 * i + l15 + dw - 1);
#pragma unroll
            for (int kk = 0; kk < 2; ++kk) {
                int gq = kk * 4 + quad;
                aoff[dw][i][kk] = gq * 128 + (w_ ^ (gq & 7));
            }
        }
    int boff[4][2];
#pragma unroll
    for (int j = 0; j < 4; ++j) {
        int oc_l = nol + 16 * j + l15;
#pragma unroll
        for (int kk = 0; kk < 2; ++kk)
            boff[j][kk] = oc_l * 8 + ((kk * 4 + quad) ^ (oc_l & 7));
    }

    const char* zb = (const char*)z + (size_t)b * (NG * NH * NW * CPG * 2);  // 8 MB/image
    const char* zr[3];
#pragma unroll
    for (int dh = 0; dh < 3; ++dh)
        zr[dh] = zb + (size_t)refl128(h + dh - 1) * (NW * CPG * 2);          // 2 KB/row seg
    const char* wt = (const char*)wtT + nb * 65536;    // oc-half base; tap stride 131072

    auto stageA = [&](const char* g) {
#pragma unroll
        for (int it = 0; it < 4; ++it)
            async_load16(g + srcA[it], (void*)(sAv + ldsoff[it]));
    };
    auto stageB = [&](const char* g, int bsel) {
#pragma unroll
        for (int it = 0; it < 4; ++it)
            async_load16(g + srcB[it], (void*)(sBv[bsel] + ldsoff[it]));
    };

    f32x4 acc[4][4] = {};

    auto compute = [&](const int (&ao)[4][2], int bsel) {
        const s16x8* bbase = sBv[bsel];
#pragma unroll
        for (int kk = 0; kk < 2; ++kk) {
            s16x8 av[4], bv[4];
#pragma unroll
            for (int i = 0; i < 4; ++i) av[i] = sAv[ao[i][kk]];
#pragma unroll
            for (int j = 0; j < 4; ++j) bv[j] = bbase[boff[j][kk]];
#pragma unroll
            for (int i = 0; i < 4; ++i)
#pragma unroll
                for (int j = 0; j < 4; ++j)
                    acc[i][j] = __builtin_amdgcn_mfma_f32_16x16x32_bf16(
                        av[i], bv[j], acc[i][j], 0, 0, 0);
        }
    };

    int buf = 0;
    stageA(zr[0]);                             // (dh=0, kc=0)
    stageB(wt, 0);
    __syncthreads();

    for (int sc = 0; sc < 12; ++sc) {
        const int dh = sc >> 2, kc = sc & 3;
        const char* bt = wt + (size_t)(dh * 3) * 131072 + kc * 128;
        stageB(bt + 131072, buf ^ 1);          // prefetch dw=1
        compute(aoff[0], buf);
        __syncthreads(); buf ^= 1;
        stageB(bt + 262144, buf ^ 1);          // prefetch dw=2
        compute(aoff[1], buf);
        __syncthreads(); buf ^= 1;
        compute(aoff[2], buf);
        __syncthreads();
        if (sc < 11) {                         // stage next (dh,kc): A + first B
            const int sn = sc + 1, dhn = sn >> 2, kcn = sn & 3;
            stageA(zr[dhn] + (size_t)kcn * 2097152);   // kc selects g-block of 8 (2 MB)
            stageB(wt + (size_t)(dhn * 3) * 131072 + kcn * 128, buf ^ 1);
            __syncthreads();
        }
        buf ^= 1;
    }

    // epilogue: D layout col=lane&15 (oc), row=quad*4+reg (w)
#pragma unroll
    for (int j = 0; j < 4; ++j) {
        int oc = n0 + 16 * j + l15;
        float bvl = cb[oc];
#pragma unroll
        for (int i = 0; i < 4; ++i) {
            int w0 = mo + 16 * i + quad * 4;
            float* dst = out + (((size_t)(b * NOUT + oc) * NH + h) * NW + w0);
            f32x4 v = acc[i][j];
            float4 o4 = { v[0] + bvl, v[1] + bvl, v[2] + bvl, v[3] + bvl };
            *(float4*)dst = o4;
        }
    }
}

// ---------------------------------------------------------------- launch
extern "C" void kernel_launch(void* const* d_in, const int* in_sizes, int n_in,
                              void* d_out, int out_size, void* d_ws, size_t ws_size,
                              hipStream_t stream) {
    const float* x   = (const float*)d_in[0];
    const float* wsp = (const float*)d_in[1];
    const float* wpw = (const float*)d_in[2];
    const float* bia = (const float*)d_in[3];
    const float* cw  = (const float*)d_in[4];
    const float* cb  = (const float*)d_in[5];
    float* out = (float*)d_out;

    // workspace layout (16B aligned):
    //   stats 16 KB | wfrag 768 KB | bias16 16 KB | wtT 1.13 MB | z 64 MB
    char* ws = (char*)d_ws;
    float*          stats  = (float*)ws;                          // 2048*2 f32
    unsigned short* wfrag  = (unsigned short*)(ws + 16384);       // 256*3*64*8 bf16
    float*          bias16 = (float*)(ws + 802816);               // 256*16 f32
    unsigned short* wtT    = (unsigned short*)(ws + 819200);      // 9*256*256 bf16
    unsigned short* z      = (unsigned short*)(ws + 1998848);     // [8][32][128][128][8]

    stats_k <<<NB * NC, 256, 0, stream>>>(x, stats);
    wfrag_k <<<208,     256, 0, stream>>>(wsp, wpw, bia, wfrag, bias16);
    repack_k<<<256,     256, 0, stream>>>(cw, wtT);
    ada_k   <<<NB * NG * 4, 256, 0, stream>>>(x, stats, wfrag, bias16, z);
    final_k <<<NB * NH * 2, 256, 0, stream>>>(z, wtT, cb, out);
}

// Round 8
// 425.267 us; speedup vs baseline: 1.4676x; 1.0307x over previous
//
#include <hip/hip_runtime.h>
#include <stdint.h>
#include <stddef.h>

// Problem: AdaConv2d  B=8 C=256 H=W=128 G=32 CPG=8 K=3 OUT=256
// Pipeline: instance-norm -> per-sample adaptive grouped 3x3 (+1x1 grouped +bias)
//           -> static 3x3 conv 256->256, reflect padding everywhere.
//
// KEY RESTRUCTURE (R8): instance-norm is folded into the adaptive conv weights:
//   out = sum W*rstd*x_bf16  -  sum_ic mean[ic]*rstd[ic]*(sum_tap W[ic,tap,oc]) + bias
// so x (512 MB fp32) is read ONCE:
//   castz_k: read x, accumulate per-channel sum/sumsq (atomics), write bf16 cast
//            channels-last xn [b][g][h][w][8] (coalesced 16B stores).
//   ada_k:   stage xn tiles via dense global_load_lds, scale W-frags by rstd in
//            regs, MFMA, add adjusted bias, write z.
//   final_k: unchanged structure (R1), + __launch_bounds__(256,3) to pin regalloc.
// xn slab is batched over b to fit ws_size (largest of {8,4,2,1} b per launch).

typedef __attribute__((ext_vector_type(8))) short   s16x8;  // 8 bf16 in 4 VGPRs
typedef __attribute__((ext_vector_type(4))) float   f32x4;

#define NB   8
#define NC   256
#define NH   128
#define NW   128
#define NG   32
#define CPG  8
#define NOUT 256
#define HWPLANE (NH*NW)          // 16384

__device__ __forceinline__ unsigned short f2bf(float f) {
    union { float f; unsigned u; } v; v.f = f;
    unsigned u = v.u;
    u += 0x7fffu + ((u >> 16) & 1u);   // RNE
    return (unsigned short)(u >> 16);
}

__device__ __forceinline__ int refl128(int i) {
    return i < 0 ? 1 : (i > 127 ? 126 : i);
}

__device__ __forceinline__ void async_load16(const void* g, void* l) {
    __builtin_amdgcn_global_load_lds(
        (const __attribute__((address_space(1))) unsigned int*)g,
        (__attribute__((address_space(3))) unsigned int*)l,
        16, 0, 0);
}

// ---------------------------------------------------------------- cast + stats
// block = (b_local, g, h-quarter): reads 8 planes' quarter, writes bf16
// channels-last xn (coalesced uint4), accumulates per-channel sum/sumsq
// (wave shfl reduce -> LDS -> atomicAdd, device scope).
__global__ __launch_bounds__(256) void castz_k(const float* __restrict__ x,
                                               float* __restrict__ sacc,
                                               unsigned short* __restrict__ xn,
                                               int b0, int nbloc, int lognb) {
    const int id = blockIdx.x;
    const int bl = id & (nbloc - 1);
    const int g  = (id >> lognb) & 31;
    const int qh = id >> (lognb + 5);        // 0..3
    const int bgG = (b0 + bl) * 32 + g;
    const int bgL = bl * 32 + g;
    const int tid = threadIdx.x;
    const int lane = tid & 63;
    const int wv   = tid >> 6;

    const size_t pb  = (size_t)bgG * 8 * HWPLANE + qh * 4096;
    unsigned short* xq = xn + ((size_t)bgL * HWPLANE + qh * 4096) * 8;

    float s[8] = {}, q2[8] = {};
#pragma unroll 4
    for (int i = 0; i < 16; ++i) {
        int pix = i * 256 + tid;
        unsigned short u[8];
#pragma unroll
        for (int ic = 0; ic < 8; ++ic) {
            float v = x[pb + (size_t)ic * HWPLANE + pix];
            s[ic] += v; q2[ic] += v * v;
            u[ic] = f2bf(v);
        }
        uint4 pk;
        pk.x = (unsigned)u[0] | ((unsigned)u[1] << 16);
        pk.y = (unsigned)u[2] | ((unsigned)u[3] << 16);
        pk.z = (unsigned)u[4] | ((unsigned)u[5] << 16);
        pk.w = (unsigned)u[6] | ((unsigned)u[7] << 16);
        *(uint4*)(xq + (size_t)pix * 8) = pk;    // consecutive lanes: 16B coalesced
    }
    // wave reduce 16 partials
#pragma unroll
    for (int o = 32; o; o >>= 1) {
#pragma unroll
        for (int ic = 0; ic < 8; ++ic) {
            s[ic]  += __shfl_xor(s[ic],  o, 64);
            q2[ic] += __shfl_xor(q2[ic], o, 64);
        }
    }
    __shared__ float red[4][16];
    if (lane == 0) {
#pragma unroll
        for (int ic = 0; ic < 8; ++ic) {
            red[wv][ic * 2]     = s[ic];
            red[wv][ic * 2 + 1] = q2[ic];
        }
    }
    __syncthreads();
    if (tid < 16) {
        float t = red[0][tid] + red[1][tid] + red[2][tid] + red[3][tid];
        int ic = tid >> 1, sel = tid & 1;
        atomicAdd(&sacc[((size_t)bgG * 8 + ic) * 2 + sel], t);
    }
}

// ---------------------------------------------------------------- wfrag (f32) + bias16 + S
// wfragF[bg][kw][lane][e] = weff(bg, ic=e, tap=kw*4+(l>>4), oc=l&15)  (f32!)
// bias16[bg][16]: bias zero-padded. S[bg][oc16][ic8] = sum_tap weff (0 for oc>=8).
__global__ __launch_bounds__(256) void wfrag_k(const float* __restrict__ wsp,
                                               const float* __restrict__ wpw,
                                               const float* __restrict__ bias,
                                               float* __restrict__ wfragF,
                                               float* __restrict__ bias16,
                                               float* __restrict__ S) {
    int tid = blockIdx.x * 256 + threadIdx.x;   // 86016 total (336 blocks)
    if (tid < 49152) {
        int lane = tid & 63;
        int kw   = (tid >> 6) % 3;
        int bg   = tid / 192;
        int oc   = lane & 15;
        int tap  = kw * 4 + (lane >> 4);
        float fr[8];
#pragma unroll
        for (int e = 0; e < 8; ++e) {
            float v = 0.f;
            if (tap < 9 && oc < 8) {
#pragma unroll
                for (int j = 0; j < 8; ++j)
                    v += wpw[(bg * 8 + oc) * 8 + j] *
                         wsp[((bg * 8 + j) * 8 + e) * 9 + tap];
            }
            fr[e] = v;
        }
        float* dst = wfragF + (size_t)((bg * 3 + kw) * 64 + lane) * 8;
        *(float4*)dst       = make_float4(fr[0], fr[1], fr[2], fr[3]);
        *(float4*)(dst + 4) = make_float4(fr[4], fr[5], fr[6], fr[7]);
    } else if (tid < 53248) {
        int t2 = tid - 49152;                    // 0..4095
        int bg = t2 >> 4, j = t2 & 15;
        bias16[bg * 16 + j] = (j < 8) ? bias[bg * 8 + j] : 0.f;
    } else {
        int t3 = tid - 53248;                    // 0..32767
        int ic = t3 & 7;
        int oc = (t3 >> 3) & 15;
        int bg = t3 >> 7;
        float v = 0.f;
        if (oc < 8) {
#pragma unroll
            for (int j = 0; j < 8; ++j) {
                float wj = wpw[(bg * 8 + oc) * 8 + j];
                float ts = 0.f;
#pragma unroll
                for (int tap = 0; tap < 9; ++tap)
                    ts += wsp[((bg * 8 + j) * 8 + ic) * 9 + tap];
                v += wj * ts;
            }
        }
        S[(size_t)(bg * 16 + oc) * 8 + ic] = v;
    }
}

// ---------------------------------------------------------------- weight repack
// conv_w [O][C][3][3] fp32 -> wtT [tap][O][C] bf16, via LDS transpose.
__global__ __launch_bounds__(256) void repack_k(const float* __restrict__ cw,
                                                unsigned short* __restrict__ wtT) {
    __shared__ float ld[2304];
    const int blk = blockIdx.x;                 // 256 blocks
    const float* src = cw + (size_t)blk * 2304;
#pragma unroll
    for (int it = 0; it < 9; ++it)
        ld[it * 256 + threadIdx.x] = src[it * 256 + threadIdx.x];
    __syncthreads();
    int p = blk * 256 + threadIdx.x;            // (o,c) pair index
    int o = p >> 8, c = p & 255;
#pragma unroll
    for (int t = 0; t < 9; ++t)
        wtT[((size_t)t * NOUT + o) * NC + c] = f2bf(ld[threadIdx.x * 9 + t]);
}

// ---------------------------------------------------------------- adaptive conv (MFMA, norm folded)
// block = (b_local, g, q 0..3): 256 thr / 4 waves, output rows h0=q*32 .. +31.
// LDS tile [34 rows][128 w][8 ic] bf16 (68 KB), staged from xn via dense
// global_load_lds (2 KB/row contiguous). W-frags loaded f32, scaled by rstd,
// rounded to bf16 once. Bias adjusted: badj = bias - sum_ic mean*rstd*S[ic,oc].
__global__ __launch_bounds__(256) void ada_k(const unsigned short* __restrict__ xn,
                                             const float* __restrict__ sacc,
                                             const float* __restrict__ wfragF,
                                             const float* __restrict__ bias16,
                                             const float* __restrict__ S,
                                             unsigned short* __restrict__ z,
                                             int b0, int nbloc, int lognb) {
    __shared__ s16x8 tile[34 * 128];        // 68 KB
    const int id = blockIdx.x;
    const int bl = id & (nbloc - 1);
    const int g  = (id >> lognb) & 31;
    const int q  = id >> (lognb + 5);
    const int bgG = (b0 + bl) * 32 + g;
    const int bgL = bl * 32 + g;
    const int h0 = q * 32;

    const int tid  = threadIdx.x;
    const int lane = tid & 63;
    const int wv   = tid >> 6;
    const int l15  = lane & 15;
    const int quad = lane >> 4;

    // stage 34 rows x 2 KB from xn (dense global_load_lds, linear LDS dest)
    const char* xnbg = (const char*)xn + (size_t)bgL * HWPLANE * 16;
    {
        const int rsub = tid >> 7;          // 0/1
        const int wcol = tid & 127;
#pragma unroll
        for (int it = 0; it < 17; ++it) {
            int r  = it * 2 + rsub;
            int gr = refl128(h0 - 1 + r);
            const char* src = xnbg + (size_t)gr * 2048 + wcol * 16;
            async_load16(src, (void*)(tile + it * 256 + wv * 64));
        }
    }

    // stats -> rstd, mean*rstd (block-uniform)
    float rst[8], msr[8];
#pragma unroll
    for (int ic = 0; ic < 8; ++ic) {
        float sm = sacc[((size_t)bgG * 8 + ic) * 2];
        float sq = sacc[((size_t)bgG * 8 + ic) * 2 + 1];
        float mean = sm * (1.f / HWPLANE);
        float var  = sq * (1.f / HWPLANE) - mean * mean;
        float r = rsqrtf(var + 1e-5f);
        rst[ic] = r;
        msr[ic] = mean * r;
    }

    // W fragments: f32 load, scale by rstd[ic=e], round once to bf16
    s16x8 wf[3];
#pragma unroll
    for (int kw = 0; kw < 3; ++kw) {
        const float* wp = wfragF + (size_t)((bgG * 3 + kw) * 64 + lane) * 8;
        float4 a = *(const float4*)wp;
        float4 c = *(const float4*)(wp + 4);
        unsigned short e0 = f2bf(a.x * rst[0]), e1 = f2bf(a.y * rst[1]);
        unsigned short e2 = f2bf(a.z * rst[2]), e3 = f2bf(a.w * rst[3]);
        unsigned short e4 = f2bf(c.x * rst[4]), e5 = f2bf(c.y * rst[5]);
        unsigned short e6 = f2bf(c.z * rst[6]), e7 = f2bf(c.w * rst[7]);
        union { uint4 u; s16x8 v; } pk;
        pk.u.x = (unsigned)e0 | ((unsigned)e1 << 16);
        pk.u.y = (unsigned)e2 | ((unsigned)e3 << 16);
        pk.u.z = (unsigned)e4 | ((unsigned)e5 << 16);
        pk.u.w = (unsigned)e6 | ((unsigned)e7 << 16);
        wf[kw] = pk.v;
    }

    // adjusted bias for this lane's 4 oc rows (oc = quad*4+r; rows>=8 unused/zero)
    float badj[4];
#pragma unroll
    for (int r = 0; r < 4; ++r) {
        int oc = quad * 4 + r;
        const float* sp = S + (size_t)(bgG * 16 + oc) * 8;
        float a = bias16[bgG * 16 + oc];
#pragma unroll
        for (int ic = 0; ic < 8; ++ic) a -= msr[ic] * sp[ic];
        badj[r] = a;
    }

    // per-lane tap geometry: tap = kw*4 + quad
    int dhA[3], dwm[3];
#pragma unroll
    for (int kw = 0; kw < 3; ++kw) {
        int tap = kw * 4 + quad;
        if (tap < 9) { dhA[kw] = tap / 3; dwm[kw] = tap % 3 - 1; }
        else         { dhA[kw] = 0;       dwm[kw] = 0; }        // zero W-frag
    }

    __syncthreads();

#pragma unroll 2
    for (int i = 0; i < 64; ++i) {
        int pb = wv * 64 + i;               // pixel block: 16 pixels
        int ro = pb >> 3;                   // 0..31 output row in tile
        int w0 = (pb & 7) * 16;
        f32x4 acc = {};
#pragma unroll
        for (int kw = 0; kw < 3; ++kw) {
            int wr = refl128(w0 + l15 + dwm[kw]);
            s16x8 xf = tile[(ro + dhA[kw]) * 128 + wr];
            acc = __builtin_amdgcn_mfma_f32_16x16x32_bf16(wf[kw], xf, acc, 0, 0, 0);
        }
        unsigned short o0 = f2bf(acc[0] + badj[0]);
        unsigned short o1 = f2bf(acc[1] + badj[1]);
        unsigned short o2 = f2bf(acc[2] + badj[2]);
        unsigned short o3 = f2bf(acc[3] + badj[3]);
        if (lane < 32) {
            uint2 pk2 = { (unsigned)o0 | ((unsigned)o1 << 16),
                          (unsigned)o2 | ((unsigned)o3 << 16) };
            unsigned short* zp = z + ((size_t)(bgG * NH + h0 + ro) * NW + w0 + l15) * 8
                                   + quad * 4;
            *(uint2*)zp = pk2;
        }
    }
}

// ---------------------------------------------------------------- final conv (LDS-tiled MFMA implicit GEMM)
// R1 structure. grid 2048: b = id&7 (XCD pin), j = id>>3, nb = j&1, h = j>>1.
// block 256 thr / 4 waves, tile 128 w x 128 oc, wave 64x64, BK=64.
// LDS: A 16 KB (single) + B 2x16 KB (dbuf) = 48 KB -> 3 blocks/CU.
// __launch_bounds__(256,3) pins regalloc toward R0's VGPR 76 codegen.
__global__ __launch_bounds__(256, 3) void final_k(const unsigned short* __restrict__ z,
                                                  const unsigned short* __restrict__ wtT,
                                                  const float* __restrict__ cb,
                                                  float* __restrict__ out) {
    __shared__ s16x8 sAv[1024];        // 8 gq x 128 w chunks (16 B), XOR-swizzled
    __shared__ s16x8 sBv[2][1024];

    const int id = blockIdx.x;
    const int b  = id & 7;
    const int jb = id >> 3;
    const int nb = jb & 1;
    const int h  = jb >> 1;

    const int tid  = threadIdx.x;
    const int wv   = tid >> 6;
    const int lane = tid & 63;
    const int l15  = lane & 15;
    const int quad = lane >> 4;
    const int mo   = (wv & 1) << 6;          // w offset of wave tile
    const int nol  = (wv >> 1) << 6;         // oc offset within 128-oc block tile
    const int n0   = (nb << 7) + nol;        // global oc base of wave tile

    // B staging (wtT [tap][o][c], o-major rows of 512 B): per-lane swizzled source
    int srcB[4], ldsoff[4];
#pragma unroll
    for (int it = 0; it < 4; ++it) {
        int ch  = it * 256 + tid;
        int row = ch >> 3, cp = ch & 7;
        srcB[it]   = row * 512 + ((cp ^ (row & 7)) << 4);
        ldsoff[it] = it * 256 + wv * 64;     // chunk index of wave's uniform base
    }

    // A staging (z [g][h][w][8]): chunk = gq*128 + wslot holds global w = wslot^(gq&7)
    int srcA[4];
#pragma unroll
    for (int it = 0; it < 4; ++it) {
        int ch = it * 256 + tid;
        int gq = ch >> 7, wslot = ch & 127;
        srcA[it] = gq * 262144 + ((wslot ^ (gq & 7)) << 4);   // g stride 256 KB
    }

    int aoff[3][4][2];
#pragma unroll
    for (int dw = 0; dw < 3; ++dw)
#pragma unroll
        for (int i = 0; i < 4; ++i) {
            int w_ = refl128(mo + 16 * i + l15 + dw - 1);
#pragma unroll
            for (int kk = 0; kk < 2; ++kk) {
                int gq = kk * 4 + quad;
                aoff[dw][i][kk] = gq * 128 + (w_ ^ (gq & 7));
            }
        }
    int boff[4][2];
#pragma unroll
    for (int j = 0; j < 4; ++j) {
        int oc_l = nol + 16 * j + l15;
#pragma unroll
        for (int kk = 0; kk < 2; ++kk)
            boff[j][kk] = oc_l * 8 + ((kk * 4 + quad) ^ (oc_l & 7));
    }

    const char* zb = (const char*)z + (size_t)b * (NG * NH * NW * CPG * 2);  // 8 MB/image
    const char* zr[3];
#pragma unroll
    for (int dh = 0; dh < 3; ++dh)
        zr[dh] = zb + (size_t)refl128(h + dh - 1) * (NW * CPG * 2);          // 2 KB/row seg
    const char* wt = (const char*)wtT + nb * 65536;    // oc-half base; tap stride 131072

    auto stageA = [&](const char* g) {
#pragma unroll
        for (int it = 0; it < 4; ++it)
            async_load16(g + srcA[it], (void*)(sAv + ldsoff[it]));
    };
    auto stageB = [&](const char* g, int bsel) {
#pragma unroll
        for (int it = 0; it < 4; ++it)
            async_load16(g + srcB[it], (void*)(sBv[bsel] + ldsoff[it]));
    };

    f32x4 acc[4][4] = {};

    auto compute = [&](const int (&ao)[4][2], int bsel) {
        const s16x8* bbase = sBv[bsel];
#pragma unroll
        for (int kk = 0; kk < 2; ++kk) {
            s16x8 av[4], bv[4];
#pragma unroll
            for (int i = 0; i < 4; ++i) av[i] = sAv[ao[i][kk]];
#pragma unroll
            for (int j = 0; j < 4; ++j) bv[j] = bbase[boff[j][kk]];
#pragma unroll
            for (int i = 0; i < 4; ++i)
#pragma unroll
                for (int j = 0; j < 4; ++j)
                    acc[i][j] = __builtin_amdgcn_mfma_f32_16x16x32_bf16(
                        av[i], bv[j], acc[i][j], 0, 0, 0);
        }
    };

    int buf = 0;
    stageA(zr[0]);                             // (dh=0, kc=0)
    stageB(wt, 0);
    __syncthreads();

    for (int sc = 0; sc < 12; ++sc) {
        const int dh = sc >> 2, kc = sc & 3;
        const char* bt = wt + (size_t)(dh * 3) * 131072 + kc * 128;
        stageB(bt + 131072, buf ^ 1);          // prefetch dw=1
        compute(aoff[0], buf);
        __syncthreads(); buf ^= 1;
        stageB(bt + 262144, buf ^ 1);          // prefetch dw=2
        compute(aoff[1], buf);
        __syncthreads(); buf ^= 1;
        compute(aoff[2], buf);
        __syncthreads();
        if (sc < 11) {                         // stage next (dh,kc): A + first B
            const int sn = sc + 1, dhn = sn >> 2, kcn = sn & 3;
            stageA(zr[dhn] + (size_t)kcn * 2097152);   // kc selects g-block of 8 (2 MB)
            stageB(wt + (size_t)(dhn * 3) * 131072 + kcn * 128, buf ^ 1);
            __syncthreads();
        }
        buf ^= 1;
    }

    // epilogue: D layout col=lane&15 (oc), row=quad*4+reg (w)
#pragma unroll
    for (int j = 0; j < 4; ++j) {
        int oc = n0 + 16 * j + l15;
        float bvl = cb[oc];
#pragma unroll
        for (int i = 0; i < 4; ++i) {
            int w0 = mo + 16 * i + quad * 4;
            float* dst = out + (((size_t)(b * NOUT + oc) * NH + h) * NW + w0);
            f32x4 v = acc[i][j];
            float4 o4 = { v[0] + bvl, v[1] + bvl, v[2] + bvl, v[3] + bvl };
            *(float4*)dst = o4;
        }
    }
}

// ---------------------------------------------------------------- launch
extern "C" void kernel_launch(void* const* d_in, const int* in_sizes, int n_in,
                              void* d_out, int out_size, void* d_ws, size_t ws_size,
                              hipStream_t stream) {
    const float* x   = (const float*)d_in[0];
    const float* wsp = (const float*)d_in[1];
    const float* wpw = (const float*)d_in[2];
    const float* bia = (const float*)d_in[3];
    const float* cw  = (const float*)d_in[4];
    const float* cb  = (const float*)d_in[5];
    float* out = (float*)d_out;

    // workspace layout (16B aligned):
    //   sacc 16K | wfragF 1.5M | bias16 16K | S 128K | wtT 1.13M | z 64M | xn <=128M
    char* ws = (char*)d_ws;
    float*          sacc   = (float*)ws;                          // 2048*2 f32
    float*          wfragF = (float*)(ws + 16384);                // 256*3*64*8 f32
    float*          bias16 = (float*)(ws + 1589248);              // 256*16 f32
    float*          S      = (float*)(ws + 1605632);              // 256*16*8 f32
    unsigned short* wtT    = (unsigned short*)(ws + 1736704);     // 9*256*256 bf16
    unsigned short* z      = (unsigned short*)(ws + 2916352);     // [8][32][128][128][8]
    unsigned short* xn     = (unsigned short*)(ws + 70025216);    // [nbloc][32][128][128][8]

    // pick largest b-batch whose xn slab fits the workspace
    int nbloc = 8, lognb = 3;
    while (nbloc > 1 &&
           70025216ull + (size_t)nbloc * 16777216ull > ws_size) { nbloc >>= 1; --lognb; }

    hipMemsetAsync(sacc, 0, 16384, stream);
    wfrag_k <<<336, 256, 0, stream>>>(wsp, wpw, bia, wfragF, bias16, S);
    repack_k<<<256, 256, 0, stream>>>(cw, wtT);
    for (int b0 = 0; b0 < NB; b0 += nbloc) {
        castz_k<<<nbloc * 128, 256, 0, stream>>>(x, sacc, xn, b0, nbloc, lognb);
        ada_k  <<<nbloc * 128, 256, 0, stream>>>(xn, sacc, wfragF, bias16, S, z,
                                                 b0, nbloc, lognb);
    }
    final_k <<<NB * NH * 2, 256, 0, stream>>>(z, wtT, cb, out);
}